// Round 19
// baseline (794.659 us; speedup 1.0000x reference)
//
#include <hip/hip_runtime.h>
#include <hip/hip_bf16.h>
#include <math.h>

// TinyRecursiveModelTRMv3 — Round 19: R18 (best, 786us) + two more
// live-range reductions targeting the remaining ~45MB/dispatch spill:
//   1) P0 staged sequentially (x, then y, then z): peak live 48 -> ~8 floats
//   2) T4 LN256 two-pass over LDS (no yf[16]/zf[16] arrays)

constexpr int NB = 32768;
constexpr int ND = 128;
constexpr float LNEPS = 1e-5f;

typedef short bf16x8 __attribute__((ext_vector_type(8)));
typedef float f32x4 __attribute__((ext_vector_type(4)));
typedef unsigned uint4v __attribute__((ext_vector_type(4)));
using bf16 = __hip_bfloat16;

static __device__ __forceinline__ float gelu_erf(float x) {
  return 0.5f * x * (1.0f + erff(x * 0.70710678118654752440f));
}
static __device__ __forceinline__ float sigmoidf_(float x) {
  return 1.0f / (1.0f + expf(-x));
}
static __device__ __forceinline__ f32x4 mfma16(bf16x8 a, bf16x8 b, f32x4 c) {
  return __builtin_amdgcn_mfma_f32_16x16x32_bf16(a, b, c, 0, 0, 0);
}
static __device__ __forceinline__ float bfs2f(short u) {
  unsigned v = ((unsigned)(unsigned short)u) << 16;
  return __builtin_bit_cast(float, v);
}
static __device__ __forceinline__ unsigned pk_bf2(float a, float b) {
  unsigned ua = __builtin_bit_cast(unsigned, a);
  unsigned ub = __builtin_bit_cast(unsigned, b);
  ua = (ua + 0x7fffu + ((ua >> 16) & 1u)) >> 16;
  ub = (ub + 0x7fffu + ((ub >> 16) & 1u)) & 0xffff0000u;
  return ub | ua;
}

// fragment-major: f = ((n>>4)*(K>>5) + (k>>5))*512 + (n&15)*32 + (k&31)
__global__ void prep_w_frag(const float* __restrict__ src, bf16* __restrict__ dst,
                            int K, int N) {
  int i = blockIdx.x * 256 + threadIdx.x;
  if (i >= K * N) return;
  int k = i / N, n = i - k * N;
  int f = ((n >> 4) * (K >> 5) + (k >> 5)) * 512 + (n & 15) * 32 + (k & 31);
  dst[f] = __float2bfloat16(src[i]);
}

// W1' = diag(lnw)·W1 split into xy (K=256) and z (K=128), frag-major
__global__ void prep_w1p(const float* __restrict__ W1, const float* __restrict__ lnw,
                         bf16* __restrict__ WXY, bf16* __restrict__ WZ) {
  int i = blockIdx.x * 256 + threadIdx.x;
  if (i >= 384 * 256) return;
  int j = i >> 8, n = i & 255;
  float v = lnw[j] * W1[i];
  if (j < 256) {
    int f = ((n >> 4) * 8 + (j >> 5)) * 512 + (n & 15) * 32 + (j & 31);
    WXY[f] = __float2bfloat16(v);
  } else {
    int k = j - 256;
    int f = ((n >> 4) * 4 + (k >> 5)) * 512 + (n & 15) * 32 + (k & 31);
    WZ[f] = __float2bfloat16(v);
  }
}

__global__ void prep_uv(const float* __restrict__ W1, const float* __restrict__ lnw,
                        const float* __restrict__ lnb, const float* __restrict__ b1,
                        float* __restrict__ U, float* __restrict__ V0b) {
  int n = threadIdx.x;
  float u = 0.f, v = 0.f;
  for (int j = 0; j < 384; ++j) {
    float w = W1[j * 256 + n];
    u = fmaf(lnw[j], w, u);
    v = fmaf(lnb[j], w, v);
  }
  U[n] = u;
  V0b[n] = v + b1[n];
}

// ---------------------------------------------------------------- trm_step
// LDS pool (153600 B) — R18 layout:
//   zs f32[64][132] @0 | ys f32[64][132] @33792 | scr @67584 (84992):
//     latent: pxy[64][264] @+0, znbL[64][136] @+33792, hx[64][264] @+51200
//     tail:   znbT @+0, qvb @+17408, kcb @+34816, vcb @+52224
//             ai[64][264] @+0, ha[64][264] @+33792
//     pad(k=4): h1 f32[64][68] @+0
//   sxy @152576 | mr @153088
__global__ __launch_bounds__(512) void trm_step(
    const float* __restrict__ x, float* __restrict__ y,
    float* __restrict__ z,
    const bf16* __restrict__ W1XYF, const bf16* __restrict__ W1ZF,
    const float* __restrict__ U, const float* __restrict__ V0b,
    const bf16* __restrict__ W2F, const float* __restrict__ b2,
    const float* __restrict__ lzw, const float* __restrict__ lzb,
    const float* __restrict__ av_g,
    const float* __restrict__ lnw_ans, const float* __restrict__ lnb_ans,
    const bf16* __restrict__ WA1F, const float* __restrict__ ba1,
    const bf16* __restrict__ WA2F, const float* __restrict__ ba2,
    const float* __restrict__ Wap, const float* __restrict__ bap,
    const float* __restrict__ Wag, const float* __restrict__ bag,
    const bf16* __restrict__ WqF, const float* __restrict__ bq,
    const bf16* __restrict__ WkF, const float* __restrict__ bk,
    const bf16* __restrict__ WvF, const float* __restrict__ bv,
    const float* __restrict__ Wp1, const float* __restrict__ bp1,
    const float* __restrict__ Wp2, const float* __restrict__ bp2,
    float* __restrict__ pad_out,
    float* __restrict__ gate_sum,
    bf16* __restrict__ kh, bf16* __restrict__ vh, int k)
{
  __shared__ __align__(16) char pool[153600];
  __shared__ float gsum[8];
  float (* const zs)[132] = (float(*)[132])pool;
  float (* const ys)[132] = (float(*)[132])(pool + 33792);
  char* const scr = pool + 67584;
  bf16* const pxy  = (bf16*)scr;
  bf16* const znbL = (bf16*)(scr + 33792);
  bf16* const hx   = (bf16*)(scr + 51200);
  bf16* const znbT = (bf16*)scr;
  bf16* const qvb  = (bf16*)(scr + 17408);
  bf16* const kcb  = (bf16*)(scr + 34816);
  bf16* const vcb  = (bf16*)(scr + 52224);
  bf16* const ai   = (bf16*)scr;
  bf16* const ha   = (bf16*)(scr + 33792);
  float* const h1  = (float*)scr;                 // pad scratch [64][68]
  float2* const sxy = (float2*)(pool + 152576);
  float2* const mr  = (float2*)(pool + 153088);

  const int t = threadIdx.x;
  const int wave = t >> 6, lane = t & 63;
  const int row8 = t >> 3, sub8 = t & 7;
  const int arow = lane & 15, kseg = (lane >> 4) * 8, crow = (lane >> 4) * 4;
  const size_t row0 = (size_t)blockIdx.x * 64;
  const size_t gr = row0 + row8;

  // ===== P0: stage x, then y, then z (sequential: small live set) =====
  {
    float s = 0.f, ss = 0.f;
    // ---- x
#pragma unroll
    for (int q = 0; q < 4; ++q) {
      float4 v = *(const float4*)&x[gr * ND + sub8 * 16 + q * 4];
      s += v.x + v.y + v.z + v.w;
      ss += v.x * v.x + v.y * v.y + v.z * v.z + v.w * v.w;
      *(unsigned*)&hx[row8 * 264 + sub8 * 16 + q * 4]     = pk_bf2(v.x, v.y);
      *(unsigned*)&hx[row8 * 264 + sub8 * 16 + q * 4 + 2] = pk_bf2(v.z, v.w);
    }
    // ---- y
#pragma unroll
    for (int q = 0; q < 4; ++q) {
      float4 v = *(const float4*)&y[gr * ND + sub8 * 16 + q * 4];
      s += v.x + v.y + v.z + v.w;
      ss += v.x * v.x + v.y * v.y + v.z * v.z + v.w * v.w;
      *(unsigned*)&hx[row8 * 264 + 128 + sub8 * 16 + q * 4]     = pk_bf2(v.x, v.y);
      *(unsigned*)&hx[row8 * 264 + 128 + sub8 * 16 + q * 4 + 2] = pk_bf2(v.z, v.w);
      *(float4*)&ys[row8][sub8 * 16 + q * 4] = v;
    }
#pragma unroll
    for (int o = 1; o < 8; o <<= 1) { s += __shfl_xor(s, o); ss += __shfl_xor(ss, o); }
    // ---- z
    float zsum = 0.f, zss = 0.f;
#pragma unroll
    for (int q = 0; q < 4; ++q) {
      float4 v;
      if (k > 0) v = *(const float4*)&z[gr * ND + sub8 * 16 + q * 4];
      else       v = (float4){0.f, 0.f, 0.f, 0.f};
      *(float4*)&zs[row8][sub8 * 16 + q * 4] = v;
      *(unsigned*)&znbL[row8 * 136 + sub8 * 16 + q * 4]     = pk_bf2(v.x, v.y);
      *(unsigned*)&znbL[row8 * 136 + sub8 * 16 + q * 4 + 2] = pk_bf2(v.z, v.w);
      zsum += v.x + v.y + v.z + v.w;
      zss += v.x * v.x + v.y * v.y + v.z * v.z + v.w * v.w;
    }
#pragma unroll
    for (int o = 1; o < 8; o <<= 1) { zsum += __shfl_xor(zsum, o); zss += __shfl_xor(zss, o); }
    if (sub8 == 0) {
      sxy[row8] = make_float2(s, ss);
      float mm = (s + zsum) * (1.f / 384.f);
      float var = (ss + zss) * (1.f / 384.f) - mm * mm;
      mr[row8] = make_float2(mm, rsqrtf(var + LNEPS));
    }
  }
  __syncthreads();

  // ===== P1: pregemm pxy = [x,y] @ W1'xy (K=256, N=256) =====
  {
    f32x4 acc[4][2];
#pragma unroll
    for (int mi = 0; mi < 4; ++mi)
#pragma unroll
      for (int ni = 0; ni < 2; ++ni) acc[mi][ni] = (f32x4){0.f, 0.f, 0.f, 0.f};
#pragma unroll
    for (int kt = 0; kt < 8; ++kt) {
      bf16x8 a[4];
#pragma unroll
      for (int mi = 0; mi < 4; ++mi)
        a[mi] = *(const bf16x8*)&hx[(mi * 16 + arow) * 264 + kt * 32 + kseg];
#pragma unroll
      for (int ni = 0; ni < 2; ++ni) {
        bf16x8 b = *(const bf16x8*)&W1XYF[(size_t)((wave * 2 + ni) * 8 + kt) * 512 +
                                          arow * 32 + kseg];
        acc[0][ni] = mfma16(a[0], b, acc[0][ni]);
        acc[1][ni] = mfma16(a[1], b, acc[1][ni]);
        acc[2][ni] = mfma16(a[2], b, acc[2][ni]);
        acc[3][ni] = mfma16(a[3], b, acc[3][ni]);
      }
    }
#pragma unroll
    for (int ni = 0; ni < 2; ++ni) {
      int col = (wave * 2 + ni) * 16 + arow;
#pragma unroll
      for (int mi = 0; mi < 4; ++mi)
#pragma unroll
        for (int r = 0; r < 4; ++r)
          pxy[(mi * 16 + crow + r) * 264 + col] = __float2bfloat16(acc[mi][ni][r]);
    }
  }
  __syncthreads();

  float Uv[2], Vv[2];
#pragma unroll
  for (int ni = 0; ni < 2; ++ni) {
    int col = (wave * 2 + ni) * 16 + arow;
    Uv[ni] = U[col];
    Vv[ni] = V0b[col];
  }
  const float b2v = b2[wave * 16 + arow];

  // ===== 4 latent iterations =====
  for (int n = 0; n < 4; ++n) {
    // A) pz GEMM (K=128) + folded-LN epilogue -> hx = gelu(...)
    {
      f32x4 acc[4][2];
#pragma unroll
      for (int mi = 0; mi < 4; ++mi)
#pragma unroll
        for (int ni = 0; ni < 2; ++ni) acc[mi][ni] = (f32x4){0.f, 0.f, 0.f, 0.f};
#pragma unroll
      for (int kt = 0; kt < 4; ++kt) {
        bf16x8 a[4];
#pragma unroll
        for (int mi = 0; mi < 4; ++mi)
          a[mi] = *(const bf16x8*)&znbL[(mi * 16 + arow) * 136 + kt * 32 + kseg];
#pragma unroll
        for (int ni = 0; ni < 2; ++ni) {
          bf16x8 b = *(const bf16x8*)&W1ZF[(size_t)((wave * 2 + ni) * 4 + kt) * 512 +
                                           arow * 32 + kseg];
          acc[0][ni] = mfma16(a[0], b, acc[0][ni]);
          acc[1][ni] = mfma16(a[1], b, acc[1][ni]);
          acc[2][ni] = mfma16(a[2], b, acc[2][ni]);
          acc[3][ni] = mfma16(a[3], b, acc[3][ni]);
        }
      }
#pragma unroll
      for (int ni = 0; ni < 2; ++ni) {
        int col = (wave * 2 + ni) * 16 + arow;
#pragma unroll
        for (int mi = 0; mi < 4; ++mi)
#pragma unroll
          for (int r = 0; r < 4; ++r) {
            int row = mi * 16 + crow + r;
            float2 mrv = mr[row];
            float pv = __bfloat162float(pxy[row * 264 + col]);
            float hpre = mrv.y * (acc[mi][ni][r] + pv - mrv.x * Uv[ni]) + Vv[ni];
            hx[row * 264 + col] = __float2bfloat16(gelu_erf(hpre));
          }
      }
    }
    __syncthreads();

    // B) GEMM2 (K=256, N=128): zs += 0.3*(hx@W2 + b2)
    {
      f32x4 acc2[4];
#pragma unroll
      for (int mi = 0; mi < 4; ++mi) acc2[mi] = (f32x4){0.f, 0.f, 0.f, 0.f};
#pragma unroll
      for (int kt = 0; kt < 8; ++kt) {
        bf16x8 b = *(const bf16x8*)&W2F[(size_t)(wave * 8 + kt) * 512 + arow * 32 + kseg];
#pragma unroll
        for (int mi = 0; mi < 4; ++mi) {
          bf16x8 a = *(const bf16x8*)&hx[(mi * 16 + arow) * 264 + kt * 32 + kseg];
          acc2[mi] = mfma16(a, b, acc2[mi]);
        }
      }
      int col = wave * 16 + arow;
#pragma unroll
      for (int mi = 0; mi < 4; ++mi)
#pragma unroll
        for (int r = 0; r < 4; ++r)
          zs[mi * 16 + crow + r][col] += 0.3f * (acc2[mi][r] + b2v);
    }
    __syncthreads();

    // C) LN128 + znbL + next-iter LN384 stats
    {
      float4 v[4];
#pragma unroll
      for (int q = 0; q < 4; ++q) v[q] = *(const float4*)&zs[row8][sub8 * 16 + q * 4];
      float s = 0.f, ss = 0.f;
#pragma unroll
      for (int q = 0; q < 4; ++q) {
        s += v[q].x + v[q].y + v[q].z + v[q].w;
        ss += v[q].x * v[q].x + v[q].y * v[q].y + v[q].z * v[q].z + v[q].w * v[q].w;
      }
#pragma unroll
      for (int o = 1; o < 8; o <<= 1) { s += __shfl_xor(s, o); ss += __shfl_xor(ss, o); }
      float m = s * (1.f / 128.f);
      float rstd = rsqrtf(ss * (1.f / 128.f) - m * m + LNEPS);
      float os = 0.f, oss = 0.f;
#pragma unroll
      for (int q = 0; q < 4; ++q) {
        float4 w = *(const float4*)&lzw[sub8 * 16 + q * 4];
        float4 b = *(const float4*)&lzb[sub8 * 16 + q * 4];
        float4 o4;
        o4.x = (v[q].x - m) * rstd * w.x + b.x;
        o4.y = (v[q].y - m) * rstd * w.y + b.y;
        o4.z = (v[q].z - m) * rstd * w.z + b.z;
        o4.w = (v[q].w - m) * rstd * w.w + b.w;
        *(float4*)&zs[row8][sub8 * 16 + q * 4] = o4;
        *(unsigned*)&znbL[row8 * 136 + sub8 * 16 + q * 4]     = pk_bf2(o4.x, o4.y);
        *(unsigned*)&znbL[row8 * 136 + sub8 * 16 + q * 4 + 2] = pk_bf2(o4.z, o4.w);
        os += o4.x + o4.y + o4.z + o4.w;
        oss += o4.x * o4.x + o4.y * o4.y + o4.z * o4.z + o4.w * o4.w;
      }
#pragma unroll
      for (int o = 1; o < 8; o <<= 1) { os += __shfl_xor(os, o); oss += __shfl_xor(oss, o); }
      if (sub8 == 0) {
        float2 sv = sxy[row8];
        float mm = (sv.x + os) * (1.f / 384.f);
        float var = (sv.y + oss) * (1.f / 384.f) - mm * mm;
        mr[row8] = make_float2(mm, rsqrtf(var + LNEPS));
      }
    }
    __syncthreads();
  }

  // ===== T1: affect + gate + zn update (zs in LDS), znbT bf16 =====
  {
    float zf[16];
#pragma unroll
    for (int q = 0; q < 4; ++q) {
      float4 v = *(const float4*)&zs[row8][sub8 * 16 + q * 4];
      zf[q * 4 + 0] = v.x; zf[q * 4 + 1] = v.y;
      zf[q * 4 + 2] = v.z; zf[q * 4 + 3] = v.w;
    }
    float a0 = av_g[gr * 3 + 0], a1 = av_g[gr * 3 + 1], a2 = av_g[gr * 3 + 2];
    float alf[16];
    float s = 0.f;
#pragma unroll
    for (int e = 0; e < 16; ++e) {
      int c = sub8 * 16 + e;
      alf[e] = tanhf(fmaf(a0, Wap[c], fmaf(a1, Wap[128 + c], fmaf(a2, Wap[256 + c], bap[c]))));
      s += zf[e] * Wag[c] + alf[e] * Wag[128 + c];
    }
#pragma unroll
    for (int o = 1; o < 8; o <<= 1) s += __shfl_xor(s, o);
    float g = sigmoidf_(s + bag[0]);
    float gv = (sub8 == 0) ? g : 0.f;
#pragma unroll
    for (int o = 1; o < 64; o <<= 1) gv += __shfl_xor(gv, o);
    if (lane == 0) gsum[wave] = gv;
#pragma unroll
    for (int e = 0; e < 16; ++e) zf[e] = fmaf(0.3f * g, alf[e], zf[e]);
#pragma unroll
    for (int q = 0; q < 4; ++q) {
      float4 o4;
      o4.x = zf[q * 4 + 0]; o4.y = zf[q * 4 + 1];
      o4.z = zf[q * 4 + 2]; o4.w = zf[q * 4 + 3];
      *(float4*)&zs[row8][sub8 * 16 + q * 4] = o4;
      *(unsigned*)&znbT[row8 * 136 + sub8 * 16 + q * 4]     = pk_bf2(o4.x, o4.y);
      *(unsigned*)&znbT[row8 * 136 + sub8 * 16 + q * 4 + 2] = pk_bf2(o4.z, o4.w);
    }
  }
  __syncthreads();  // B_t1
  if (t == 0) {
    float gs = 0.f;
#pragma unroll
    for (int w = 0; w < 8; ++w) gs += gsum[w];
    atomicAdd(gate_sum + k, gs);
  }

  // ===== T2: QKV MFMA (M=64, N=128; wave n-tile = wave) =====
  {
    f32x4 aq[4], ak[4], av2[4];
#pragma unroll
    for (int mi = 0; mi < 4; ++mi) {
      aq[mi] = (f32x4){0.f, 0.f, 0.f, 0.f};
      ak[mi] = (f32x4){0.f, 0.f, 0.f, 0.f};
      av2[mi] = (f32x4){0.f, 0.f, 0.f, 0.f};
    }
#pragma unroll
    for (int kt = 0; kt < 4; ++kt) {
      size_t wr = (size_t)(wave * 4 + kt) * 512 + arow * 32 + kseg;
      bf16x8 bqv = *(const bf16x8*)&WqF[wr];
      bf16x8 bkv = *(const bf16x8*)&WkF[wr];
      bf16x8 bvv = *(const bf16x8*)&WvF[wr];
#pragma unroll
      for (int mi = 0; mi < 4; ++mi) {
        bf16x8 a = *(const bf16x8*)&znbT[(mi * 16 + arow) * 136 + kt * 32 + kseg];
        aq[mi] = mfma16(a, bqv, aq[mi]);
        ak[mi] = mfma16(a, bkv, ak[mi]);
        av2[mi] = mfma16(a, bvv, av2[mi]);
      }
    }
    int col = wave * 16 + arow;
    float bqs = bq[col], bks = bk[col], bvs = bv[col];
#pragma unroll
    for (int mi = 0; mi < 4; ++mi)
#pragma unroll
      for (int r = 0; r < 4; ++r) {
        int row = mi * 16 + crow + r;
        qvb[row * 136 + col] = __float2bfloat16(aq[mi][r] + bqs);
        kcb[row * 136 + col] = __float2bfloat16(ak[mi][r] + bks);
        vcb[row * 136 + col] = __float2bfloat16(av2[mi][r] + bvs);
      }
  }
  __syncthreads();  // B_t2

  // ===== T3: history writeback + attention + LN128 + z write (k<4) =====
  if (k < 4) {
    uint4v k0 = *(const uint4v*)&kcb[row8 * 136 + sub8 * 16];
    uint4v k1 = *(const uint4v*)&kcb[row8 * 136 + sub8 * 16 + 8];
    uint4v v0 = *(const uint4v*)&vcb[row8 * 136 + sub8 * 16];
    uint4v v1 = *(const uint4v*)&vcb[row8 * 136 + sub8 * 16 + 8];
    size_t off = ((size_t)k * NB + gr) * ND + sub8 * 16;
    __builtin_nontemporal_store(k0, (uint4v*)&kh[off]);
    __builtin_nontemporal_store(k1, (uint4v*)&kh[off + 8]);
    __builtin_nontemporal_store(v0, (uint4v*)&vh[off]);
    __builtin_nontemporal_store(v1, (uint4v*)&vh[off + 8]);
  }
  {
    float zf[16];
#pragma unroll
    for (int q = 0; q < 4; ++q) {
      float4 v = *(const float4*)&zs[row8][sub8 * 16 + q * 4];
      zf[q * 4 + 0] = v.x; zf[q * 4 + 1] = v.y;
      zf[q * 4 + 2] = v.z; zf[q * 4 + 3] = v.w;
    }
    if (k > 0) {
      bf16x8 qv0 = *(const bf16x8*)&qvb[row8 * 136 + sub8 * 16];
      bf16x8 qv1 = *(const bf16x8*)&qvb[row8 * 136 + sub8 * 16 + 8];
      float p[5];
#pragma unroll
      for (int s = 0; s < 5; ++s) {
        if (s > k) break;
        bf16x8 k0, k1;
        if (s == k) {
          k0 = *(const bf16x8*)&kcb[row8 * 136 + sub8 * 16];
          k1 = *(const bf16x8*)&kcb[row8 * 136 + sub8 * 16 + 8];
        } else {
          size_t off = ((size_t)s * NB + gr) * ND + sub8 * 16;
          k0 = __builtin_bit_cast(bf16x8, __builtin_nontemporal_load((const uint4v*)&kh[off]));
          k1 = __builtin_bit_cast(bf16x8, __builtin_nontemporal_load((const uint4v*)&kh[off + 8]));
        }
        float d = 0.f;
#pragma unroll
        for (int e = 0; e < 8; ++e)
          d += bfs2f(qv0[e]) * bfs2f(k0[e]) + bfs2f(qv1[e]) * bfs2f(k1[e]);
#pragma unroll
        for (int o = 1; o < 8; o <<= 1) d += __shfl_xor(d, o);
        p[s] = d * 0.088388347648318447f;
      }
      float mx = p[0];
#pragma unroll
      for (int s = 1; s < 5; ++s) if (s <= k) mx = fmaxf(mx, p[s]);
      float sum = 0.f;
#pragma unroll
      for (int s = 0; s < 5; ++s) if (s <= k) { p[s] = expf(p[s] - mx); sum += p[s]; }
      float inv = 1.f / sum;
#pragma unroll
      for (int s = 0; s < 5; ++s) {
        if (s > k) break;
        bf16x8 v0, v1;
        if (s == k) {
          v0 = *(const bf16x8*)&vcb[row8 * 136 + sub8 * 16];
          v1 = *(const bf16x8*)&vcb[row8 * 136 + sub8 * 16 + 8];
        } else {
          size_t off = ((size_t)s * NB + gr) * ND + sub8 * 16;
          v0 = __builtin_bit_cast(bf16x8, __builtin_nontemporal_load((const uint4v*)&vh[off]));
          v1 = __builtin_bit_cast(bf16x8, __builtin_nontemporal_load((const uint4v*)&vh[off + 8]));
        }
        float w = p[s] * inv;
#pragma unroll
        for (int e = 0; e < 8; ++e) {
          zf[e]     = fmaf(w, bfs2f(v0[e]), zf[e]);
          zf[8 + e] = fmaf(w, bfs2f(v1[e]), zf[8 + e]);
        }
      }
      float s2 = 0.f, ss = 0.f;
#pragma unroll
      for (int e = 0; e < 16; ++e) { s2 += zf[e]; ss += zf[e] * zf[e]; }
#pragma unroll
      for (int o = 1; o < 8; o <<= 1) { s2 += __shfl_xor(s2, o); ss += __shfl_xor(ss, o); }
      float m = s2 * (1.f / 128.f);
      float rstd = rsqrtf(ss * (1.f / 128.f) - m * m + LNEPS);
#pragma unroll
      for (int e = 0; e < 16; ++e) {
        int c = sub8 * 16 + e;
        zf[e] = (zf[e] - m) * rstd * lzw[c] + lzb[c];
      }
#pragma unroll
      for (int q = 0; q < 4; ++q) {
        float4 o4;
        o4.x = zf[q * 4 + 0]; o4.y = zf[q * 4 + 1];
        o4.z = zf[q * 4 + 2]; o4.w = zf[q * 4 + 3];
        *(float4*)&zs[row8][sub8 * 16 + q * 4] = o4;
      }
    }
    if (k < 4) {
#pragma unroll
      for (int q = 0; q < 4; ++q) {
        float4 o4;
        o4.x = zf[q * 4 + 0]; o4.y = zf[q * 4 + 1];
        o4.z = zf[q * 4 + 2]; o4.w = zf[q * 4 + 3];
        *(float4*)&z[gr * ND + sub8 * 16 + q * 4] = o4;
      }
    }
  }
  __syncthreads();  // B_t3

  // ===== T4: answer LN256 -> ai (two-pass over LDS; no register arrays) =====
  {
    float s = 0.f, ss = 0.f;
#pragma unroll
    for (int q = 0; q < 4; ++q) {
      float4 v = *(const float4*)&ys[row8][sub8 * 16 + q * 4];
      s += v.x + v.y + v.z + v.w;
      ss += v.x * v.x + v.y * v.y + v.z * v.z + v.w * v.w;
      float4 w = *(const float4*)&zs[row8][sub8 * 16 + q * 4];
      s += w.x + w.y + w.z + w.w;
      ss += w.x * w.x + w.y * w.y + w.z * w.z + w.w * w.w;
    }
#pragma unroll
    for (int o = 1; o < 8; o <<= 1) { s += __shfl_xor(s, o); ss += __shfl_xor(ss, o); }
    float m = s * (1.f / 256.f);
    float rstd = rsqrtf(ss * (1.f / 256.f) - m * m + LNEPS);
#pragma unroll
    for (int h = 0; h < 2; ++h) {
#pragma unroll
      for (int q = 0; q < 4; ++q) {
        float4 v = (h == 0)
            ? *(const float4*)&ys[row8][sub8 * 16 + q * 4]
            : *(const float4*)&zs[row8][sub8 * 16 + q * 4];
        int c0 = h * 128 + sub8 * 16 + q * 4;
        float a0 = (v.x - m) * rstd * lnw_ans[c0 + 0] + lnb_ans[c0 + 0];
        float a1 = (v.y - m) * rstd * lnw_ans[c0 + 1] + lnb_ans[c0 + 1];
        float a2 = (v.z - m) * rstd * lnw_ans[c0 + 2] + lnb_ans[c0 + 2];
        float a3 = (v.w - m) * rstd * lnw_ans[c0 + 3] + lnb_ans[c0 + 3];
        *(unsigned*)&ai[row8 * 264 + c0]     = pk_bf2(a0, a1);
        *(unsigned*)&ai[row8 * 264 + c0 + 2] = pk_bf2(a2, a3);
      }
    }
  }
  __syncthreads();  // B_t4

  // ===== T5: ans GEMM1 (M=64, K=256, N=256) -> ha =====
  {
    f32x4 acc[4][2];
#pragma unroll
    for (int mi = 0; mi < 4; ++mi)
#pragma unroll
      for (int ni = 0; ni < 2; ++ni) acc[mi][ni] = (f32x4){0.f, 0.f, 0.f, 0.f};
#pragma unroll
    for (int kt = 0; kt < 8; ++kt) {
      bf16x8 a[4];
#pragma unroll
      for (int mi = 0; mi < 4; ++mi)
        a[mi] = *(const bf16x8*)&ai[(mi * 16 + arow) * 264 + kt * 32 + kseg];
#pragma unroll
      for (int ni = 0; ni < 2; ++ni) {
        bf16x8 b = *(const bf16x8*)&WA1F[(size_t)((wave * 2 + ni) * 8 + kt) * 512 +
                                         arow * 32 + kseg];
        acc[0][ni] = mfma16(a[0], b, acc[0][ni]);
        acc[1][ni] = mfma16(a[1], b, acc[1][ni]);
        acc[2][ni] = mfma16(a[2], b, acc[2][ni]);
        acc[3][ni] = mfma16(a[3], b, acc[3][ni]);
      }
    }
#pragma unroll
    for (int ni = 0; ni < 2; ++ni) {
      int col = (wave * 2 + ni) * 16 + arow;
      float bb = ba1[col];
#pragma unroll
      for (int mi = 0; mi < 4; ++mi)
#pragma unroll
        for (int r = 0; r < 4; ++r)
          ha[(mi * 16 + crow + r) * 264 + col] =
              __float2bfloat16(gelu_erf(acc[mi][ni][r] + bb));
    }
  }
  __syncthreads();  // B_t5

  // ===== T6: ans GEMM2 (K=256, N=128): ys += 0.4*(ha@WA2 + ba2) =====
  {
    f32x4 acc[4];
#pragma unroll
    for (int mi = 0; mi < 4; ++mi) acc[mi] = (f32x4){0.f, 0.f, 0.f, 0.f};
#pragma unroll
    for (int kt = 0; kt < 8; ++kt) {
      bf16x8 b = *(const bf16x8*)&WA2F[(size_t)(wave * 8 + kt) * 512 + arow * 32 + kseg];
#pragma unroll
      for (int mi = 0; mi < 4; ++mi) {
        bf16x8 a = *(const bf16x8*)&ha[(mi * 16 + arow) * 264 + kt * 32 + kseg];
        acc[mi] = mfma16(a, b, acc[mi]);
      }
    }
    int col = wave * 16 + arow;
    float bb = ba2[col];
#pragma unroll
    for (int mi = 0; mi < 4; ++mi)
#pragma unroll
      for (int r = 0; r < 4; ++r)
        ys[mi * 16 + crow + r][col] += 0.4f * (acc[mi][r] + bb);
  }
  __syncthreads();  // B_t6

  // ===== T7: y writeback =====
#pragma unroll
  for (int q = 0; q < 4; ++q)
    *(float4*)&y[gr * ND + sub8 * 16 + q * 4] =
        *(const float4*)&ys[row8][sub8 * 16 + q * 4];

  // ===== PAD head fused at k==4 (zs holds final z in LDS) =====
  if (k == 4) {
    __syncthreads();
    {
      const int cc = t & 63, rg8 = t >> 6;
      float acc[8];
#pragma unroll
      for (int r = 0; r < 8; ++r) acc[r] = 0.f;
      for (int j0 = 0; j0 < ND; j0 += 4) {
        float w0 = Wp1[(j0 + 0) * 64 + cc], w1 = Wp1[(j0 + 1) * 64 + cc];
        float w2 = Wp1[(j0 + 2) * 64 + cc], w3 = Wp1[(j0 + 3) * 64 + cc];
#pragma unroll
        for (int r = 0; r < 8; ++r) {
          float4 a = *reinterpret_cast<const float4*>(&zs[rg8 * 8 + r][j0]);
          acc[r] = fmaf(a.x, w0, fmaf(a.y, w1, fmaf(a.z, w2, fmaf(a.w, w3, acc[r]))));
        }
      }
      float bb = bp1[cc];
#pragma unroll
      for (int r = 0; r < 8; ++r) h1[(rg8 * 8 + r) * 68 + cc] = gelu_erf(acc[r] + bb);
    }
    __syncthreads();
    {
      const int row = t >> 3, sub = t & 7;
      if (sub < 3) {
        float p = 0.f;
        for (int j = 0; j < 64; ++j) p += h1[row * 68 + j] * Wp2[j * 3 + sub];
        pad_out[(row0 + row) * 3 + sub] = tanhf(p + bp2[sub]);
      }
    }
  }
}

__global__ void finalize_confs(const float* __restrict__ gs, float* __restrict__ confs) {
  int i = threadIdx.x;
  if (i < 5) confs[i] = gs[i] * (1.0f / 32768.0f);
}

// ------------------------------------------------------------------- launch
extern "C" void kernel_launch(void* const* d_in, const int* in_sizes, int n_in,
                              void* d_out, int out_size, void* d_ws, size_t ws_size,
                              hipStream_t stream) {
  const float* x       = (const float*)d_in[0];
  const float* y_init  = (const float*)d_in[1];
  const float* av      = (const float*)d_in[2];
  const float* ln_lat_w = (const float*)d_in[3];
  const float* ln_lat_b = (const float*)d_in[4];
  const float* ln_ans_w = (const float*)d_in[5];
  const float* ln_ans_b = (const float*)d_in[6];
  const float* ln_z_w   = (const float*)d_in[7];
  const float* ln_z_b   = (const float*)d_in[8];
  const float* W_lat1 = (const float*)d_in[9];  const float* b_lat1 = (const float*)d_in[10];
  const float* W_lat2 = (const float*)d_in[11]; const float* b_lat2 = (const float*)d_in[12];
  const float* W_ans1 = (const float*)d_in[13]; const float* b_ans1 = (const float*)d_in[14];
  const float* W_ans2 = (const float*)d_in[15]; const float* b_ans2 = (const float*)d_in[16];
  const float* W_ap = (const float*)d_in[17];   const float* b_ap = (const float*)d_in[18];
  const float* W_ag = (const float*)d_in[19];   const float* b_ag = (const float*)d_in[20];
  const float* Wq = (const float*)d_in[21];     const float* bq = (const float*)d_in[22];
  const float* Wk = (const float*)d_in[23];     const float* bk = (const float*)d_in[24];
  const float* Wv = (const float*)d_in[25];     const float* bv = (const float*)d_in[26];
  const float* W_p1 = (const float*)d_in[27];   const float* b_p1 = (const float*)d_in[28];
  const float* W_p2 = (const float*)d_in[29];   const float* b_p2 = (const float*)d_in[30];

  float* y     = (float*)d_out;
  float* confs = (float*)d_out + (size_t)NB * ND;
  float* pad   = confs + 5;

  char* p = (char*)d_ws;
  float* gate_sum = (float*)p;
  float* z   = (float*)(p + 256);
  bf16* kh   = (bf16*)(p + 256 + (size_t)NB * ND * 4);
  bf16* vh   = kh + (size_t)4 * NB * ND;
  bf16* W2F  = vh + (size_t)4 * NB * ND;
  bf16* WA1F = W2F + 256 * 128;
  bf16* WA2F = WA1F + 256 * 256;
  bf16* WqF  = WA2F + 256 * 128;
  bf16* WkF  = WqF + 128 * 128;
  bf16* WvF  = WkF + 128 * 128;
  bf16* W1XYF = WvF + 128 * 128;          // 256x256
  bf16* W1ZF  = W1XYF + 256 * 256;        // 128x256
  float* U    = (float*)(W1ZF + 128 * 256);
  float* V0b  = U + 256;

  hipMemcpyAsync(y, y_init, (size_t)NB * ND * sizeof(float),
                 hipMemcpyDeviceToDevice, stream);
  hipMemsetAsync(gate_sum, 0, 32, stream);

  prep_w1p<<<(384 * 256 + 255) / 256, 256, 0, stream>>>(W_lat1, ln_lat_w, W1XYF, W1ZF);
  prep_uv<<<1, 256, 0, stream>>>(W_lat1, ln_lat_w, ln_lat_b, b_lat1, U, V0b);
  prep_w_frag<<<(256 * 128 + 255) / 256, 256, 0, stream>>>(W_lat2, W2F, 256, 128);
  prep_w_frag<<<(256 * 256 + 255) / 256, 256, 0, stream>>>(W_ans1, WA1F, 256, 256);
  prep_w_frag<<<(256 * 128 + 255) / 256, 256, 0, stream>>>(W_ans2, WA2F, 256, 128);
  prep_w_frag<<<(128 * 128 + 255) / 256, 256, 0, stream>>>(Wq, WqF, 128, 128);
  prep_w_frag<<<(128 * 128 + 255) / 256, 256, 0, stream>>>(Wk, WkF, 128, 128);
  prep_w_frag<<<(128 * 128 + 255) / 256, 256, 0, stream>>>(Wv, WvF, 128, 128);

  for (int k = 0; k < 5; ++k) {
    trm_step<<<NB / 64, 512, 0, stream>>>(
        x, y, z, W1XYF, W1ZF, U, V0b, W2F, b_lat2, ln_z_w, ln_z_b,
        av, ln_ans_w, ln_ans_b,
        WA1F, b_ans1, WA2F, b_ans2,
        W_ap, b_ap, W_ag, b_ag,
        WqF, bq, WkF, bk, WvF, bv,
        W_p1, b_p1, W_p2, b_p2, pad,
        gate_sum, kh, vh, k);
  }
  finalize_confs<<<1, 64, 0, stream>>>(gate_sum, confs);
}

// Round 20
// 774.128 us; speedup vs baseline: 1.0265x; 1.0265x over previous
//
#include <hip/hip_runtime.h>
#include <hip/hip_bf16.h>
#include <math.h>

// TinyRecursiveModelTRMv3 — Round 20: R18/19 structure + HBM traffic cuts.
//   1) z inter-step global storage bf16 (was fp32): -16.8 MB/dispatch
//   2) x pre-converted to bf16 once (prep_xb): -8.4 MB/dispatch
//   3) y memcpy removed: k==0 reads y_init directly
//   Schedule/tiling identical to the proven 786us kernel.

constexpr int NB = 32768;
constexpr int ND = 128;
constexpr float LNEPS = 1e-5f;

typedef short bf16x8 __attribute__((ext_vector_type(8)));
typedef float f32x4 __attribute__((ext_vector_type(4)));
typedef unsigned uint4v __attribute__((ext_vector_type(4)));
using bf16 = __hip_bfloat16;

static __device__ __forceinline__ float gelu_erf(float x) {
  return 0.5f * x * (1.0f + erff(x * 0.70710678118654752440f));
}
static __device__ __forceinline__ float sigmoidf_(float x) {
  return 1.0f / (1.0f + expf(-x));
}
static __device__ __forceinline__ f32x4 mfma16(bf16x8 a, bf16x8 b, f32x4 c) {
  return __builtin_amdgcn_mfma_f32_16x16x32_bf16(a, b, c, 0, 0, 0);
}
static __device__ __forceinline__ float bfs2f(short u) {
  unsigned v = ((unsigned)(unsigned short)u) << 16;
  return __builtin_bit_cast(float, v);
}
static __device__ __forceinline__ unsigned pk_bf2(float a, float b) {
  unsigned ua = __builtin_bit_cast(unsigned, a);
  unsigned ub = __builtin_bit_cast(unsigned, b);
  ua = (ua + 0x7fffu + ((ua >> 16) & 1u)) >> 16;
  ub = (ub + 0x7fffu + ((ub >> 16) & 1u)) & 0xffff0000u;
  return ub | ua;
}

// fragment-major: f = ((n>>4)*(K>>5) + (k>>5))*512 + (n&15)*32 + (k&31)
__global__ void prep_w_frag(const float* __restrict__ src, bf16* __restrict__ dst,
                            int K, int N) {
  int i = blockIdx.x * 256 + threadIdx.x;
  if (i >= K * N) return;
  int k = i / N, n = i - k * N;
  int f = ((n >> 4) * (K >> 5) + (k >> 5)) * 512 + (n & 15) * 32 + (k & 31);
  dst[f] = __float2bfloat16(src[i]);
}

// x fp32 -> bf16 (done once; trm_step reads bf16 x every step)
__global__ void prep_xb(const float* __restrict__ src, bf16* __restrict__ dst) {
  int i = blockIdx.x * 256 + threadIdx.x;   // one float4 per thread
  float4 v = *(const float4*)&src[(size_t)i * 4];
  unsigned u0 = pk_bf2(v.x, v.y), u1 = pk_bf2(v.z, v.w);
  *(unsigned*)&dst[(size_t)i * 4]     = u0;
  *(unsigned*)&dst[(size_t)i * 4 + 2] = u1;
}

// W1' = diag(lnw)·W1 split into xy (K=256) and z (K=128), frag-major
__global__ void prep_w1p(const float* __restrict__ W1, const float* __restrict__ lnw,
                         bf16* __restrict__ WXY, bf16* __restrict__ WZ) {
  int i = blockIdx.x * 256 + threadIdx.x;
  if (i >= 384 * 256) return;
  int j = i >> 8, n = i & 255;
  float v = lnw[j] * W1[i];
  if (j < 256) {
    int f = ((n >> 4) * 8 + (j >> 5)) * 512 + (n & 15) * 32 + (j & 31);
    WXY[f] = __float2bfloat16(v);
  } else {
    int k = j - 256;
    int f = ((n >> 4) * 4 + (k >> 5)) * 512 + (n & 15) * 32 + (k & 31);
    WZ[f] = __float2bfloat16(v);
  }
}

__global__ void prep_uv(const float* __restrict__ W1, const float* __restrict__ lnw,
                        const float* __restrict__ lnb, const float* __restrict__ b1,
                        float* __restrict__ U, float* __restrict__ V0b) {
  int n = threadIdx.x;
  float u = 0.f, v = 0.f;
  for (int j = 0; j < 384; ++j) {
    float w = W1[j * 256 + n];
    u = fmaf(lnw[j], w, u);
    v = fmaf(lnb[j], w, v);
  }
  U[n] = u;
  V0b[n] = v + b1[n];
}

// ---------------------------------------------------------------- trm_step
// LDS pool (153600 B) — unchanged layout:
//   zs f32[64][132] @0 | ys f32[64][132] @33792 | scr @67584 (84992):
//     latent: pxy[64][264] @+0, znbL[64][136] @+33792, hx[64][264] @+51200
//     tail:   znbT @+0, qvb @+17408, kcb @+34816, vcb @+52224
//             ai[64][264] @+0, ha[64][264] @+33792
//     pad(k=4): h1 f32[64][68] @+0
//   sxy @152576 | mr @153088
__global__ __launch_bounds__(512) void trm_step(
    const bf16* __restrict__ xb, const float* __restrict__ ysrc,
    float* __restrict__ y,
    bf16* __restrict__ zb,
    const bf16* __restrict__ W1XYF, const bf16* __restrict__ W1ZF,
    const float* __restrict__ U, const float* __restrict__ V0b,
    const bf16* __restrict__ W2F, const float* __restrict__ b2,
    const float* __restrict__ lzw, const float* __restrict__ lzb,
    const float* __restrict__ av_g,
    const float* __restrict__ lnw_ans, const float* __restrict__ lnb_ans,
    const bf16* __restrict__ WA1F, const float* __restrict__ ba1,
    const bf16* __restrict__ WA2F, const float* __restrict__ ba2,
    const float* __restrict__ Wap, const float* __restrict__ bap,
    const float* __restrict__ Wag, const float* __restrict__ bag,
    const bf16* __restrict__ WqF, const float* __restrict__ bq,
    const bf16* __restrict__ WkF, const float* __restrict__ bk,
    const bf16* __restrict__ WvF, const float* __restrict__ bv,
    const float* __restrict__ Wp1, const float* __restrict__ bp1,
    const float* __restrict__ Wp2, const float* __restrict__ bp2,
    float* __restrict__ pad_out,
    float* __restrict__ gate_sum,
    bf16* __restrict__ kh, bf16* __restrict__ vh, int k)
{
  __shared__ __align__(16) char pool[153600];
  __shared__ float gsum[8];
  float (* const zs)[132] = (float(*)[132])pool;
  float (* const ys)[132] = (float(*)[132])(pool + 33792);
  char* const scr = pool + 67584;
  bf16* const pxy  = (bf16*)scr;
  bf16* const znbL = (bf16*)(scr + 33792);
  bf16* const hx   = (bf16*)(scr + 51200);
  bf16* const znbT = (bf16*)scr;
  bf16* const qvb  = (bf16*)(scr + 17408);
  bf16* const kcb  = (bf16*)(scr + 34816);
  bf16* const vcb  = (bf16*)(scr + 52224);
  bf16* const ai   = (bf16*)scr;
  bf16* const ha   = (bf16*)(scr + 33792);
  float* const h1  = (float*)scr;                 // pad scratch [64][68]
  float2* const sxy = (float2*)(pool + 152576);
  float2* const mr  = (float2*)(pool + 153088);

  const int t = threadIdx.x;
  const int wave = t >> 6, lane = t & 63;
  const int row8 = t >> 3, sub8 = t & 7;
  const int arow = lane & 15, kseg = (lane >> 4) * 8, crow = (lane >> 4) * 4;
  const size_t row0 = (size_t)blockIdx.x * 64;
  const size_t gr = row0 + row8;

  // ===== P0: stage x(bf16), y, z(bf16); row sums; iter-0 LN384 stats =====
  {
    float s = 0.f, ss = 0.f;
    // ---- x (bf16 pre-converted; pure copy into hx + stats)
    {
      uint4v xu0 = *(const uint4v*)&xb[gr * ND + sub8 * 16];
      uint4v xu1 = *(const uint4v*)&xb[gr * ND + sub8 * 16 + 8];
      *(uint4v*)&hx[row8 * 264 + sub8 * 16]     = xu0;
      *(uint4v*)&hx[row8 * 264 + sub8 * 16 + 8] = xu1;
      bf16x8 xv0 = __builtin_bit_cast(bf16x8, xu0);
      bf16x8 xv1 = __builtin_bit_cast(bf16x8, xu1);
#pragma unroll
      for (int e = 0; e < 8; ++e) {
        float f0 = bfs2f(xv0[e]), f1 = bfs2f(xv1[e]);
        s += f0 + f1;
        ss += f0 * f0 + f1 * f1;
      }
    }
    // ---- y (fp32; from y_init at k==0, else y)
#pragma unroll
    for (int q = 0; q < 4; ++q) {
      float4 v = *(const float4*)&ysrc[gr * ND + sub8 * 16 + q * 4];
      s += v.x + v.y + v.z + v.w;
      ss += v.x * v.x + v.y * v.y + v.z * v.z + v.w * v.w;
      *(unsigned*)&hx[row8 * 264 + 128 + sub8 * 16 + q * 4]     = pk_bf2(v.x, v.y);
      *(unsigned*)&hx[row8 * 264 + 128 + sub8 * 16 + q * 4 + 2] = pk_bf2(v.z, v.w);
      *(float4*)&ys[row8][sub8 * 16 + q * 4] = v;
    }
#pragma unroll
    for (int o = 1; o < 8; o <<= 1) { s += __shfl_xor(s, o); ss += __shfl_xor(ss, o); }
    // ---- z (bf16 inter-step storage)
    float zsum = 0.f, zss = 0.f;
    {
      uint4v zu0, zu1;
      if (k > 0) {
        zu0 = *(const uint4v*)&zb[gr * ND + sub8 * 16];
        zu1 = *(const uint4v*)&zb[gr * ND + sub8 * 16 + 8];
      } else {
        zu0 = (uint4v){0u, 0u, 0u, 0u};
        zu1 = (uint4v){0u, 0u, 0u, 0u};
      }
      *(uint4v*)&znbL[row8 * 136 + sub8 * 16]     = zu0;
      *(uint4v*)&znbL[row8 * 136 + sub8 * 16 + 8] = zu1;
      bf16x8 zv0 = __builtin_bit_cast(bf16x8, zu0);
      bf16x8 zv1 = __builtin_bit_cast(bf16x8, zu1);
#pragma unroll
      for (int q = 0; q < 2; ++q) {
        float4 v;
        v.x = bfs2f(zv0[q * 4 + 0]); v.y = bfs2f(zv0[q * 4 + 1]);
        v.z = bfs2f(zv0[q * 4 + 2]); v.w = bfs2f(zv0[q * 4 + 3]);
        *(float4*)&zs[row8][sub8 * 16 + q * 4] = v;
        zsum += v.x + v.y + v.z + v.w;
        zss += v.x * v.x + v.y * v.y + v.z * v.z + v.w * v.w;
        float4 w;
        w.x = bfs2f(zv1[q * 4 + 0]); w.y = bfs2f(zv1[q * 4 + 1]);
        w.z = bfs2f(zv1[q * 4 + 2]); w.w = bfs2f(zv1[q * 4 + 3]);
        *(float4*)&zs[row8][sub8 * 16 + 8 + q * 4] = w;
        zsum += w.x + w.y + w.z + w.w;
        zss += w.x * w.x + w.y * w.y + w.z * w.z + w.w * w.w;
      }
    }
#pragma unroll
    for (int o = 1; o < 8; o <<= 1) { zsum += __shfl_xor(zsum, o); zss += __shfl_xor(zss, o); }
    if (sub8 == 0) {
      sxy[row8] = make_float2(s, ss);
      float mm = (s + zsum) * (1.f / 384.f);
      float var = (ss + zss) * (1.f / 384.f) - mm * mm;
      mr[row8] = make_float2(mm, rsqrtf(var + LNEPS));
    }
  }
  __syncthreads();

  // ===== P1: pregemm pxy = [x,y] @ W1'xy (K=256, N=256) =====
  {
    f32x4 acc[4][2];
#pragma unroll
    for (int mi = 0; mi < 4; ++mi)
#pragma unroll
      for (int ni = 0; ni < 2; ++ni) acc[mi][ni] = (f32x4){0.f, 0.f, 0.f, 0.f};
#pragma unroll
    for (int kt = 0; kt < 8; ++kt) {
      bf16x8 a[4];
#pragma unroll
      for (int mi = 0; mi < 4; ++mi)
        a[mi] = *(const bf16x8*)&hx[(mi * 16 + arow) * 264 + kt * 32 + kseg];
#pragma unroll
      for (int ni = 0; ni < 2; ++ni) {
        bf16x8 b = *(const bf16x8*)&W1XYF[(size_t)((wave * 2 + ni) * 8 + kt) * 512 +
                                          arow * 32 + kseg];
        acc[0][ni] = mfma16(a[0], b, acc[0][ni]);
        acc[1][ni] = mfma16(a[1], b, acc[1][ni]);
        acc[2][ni] = mfma16(a[2], b, acc[2][ni]);
        acc[3][ni] = mfma16(a[3], b, acc[3][ni]);
      }
    }
#pragma unroll
    for (int ni = 0; ni < 2; ++ni) {
      int col = (wave * 2 + ni) * 16 + arow;
#pragma unroll
      for (int mi = 0; mi < 4; ++mi)
#pragma unroll
        for (int r = 0; r < 4; ++r)
          pxy[(mi * 16 + crow + r) * 264 + col] = __float2bfloat16(acc[mi][ni][r]);
    }
  }
  __syncthreads();

  float Uv[2], Vv[2];
#pragma unroll
  for (int ni = 0; ni < 2; ++ni) {
    int col = (wave * 2 + ni) * 16 + arow;
    Uv[ni] = U[col];
    Vv[ni] = V0b[col];
  }
  const float b2v = b2[wave * 16 + arow];

  // ===== 4 latent iterations =====
  for (int n = 0; n < 4; ++n) {
    // A) pz GEMM (K=128) + folded-LN epilogue -> hx = gelu(...)
    {
      f32x4 acc[4][2];
#pragma unroll
      for (int mi = 0; mi < 4; ++mi)
#pragma unroll
        for (int ni = 0; ni < 2; ++ni) acc[mi][ni] = (f32x4){0.f, 0.f, 0.f, 0.f};
#pragma unroll
      for (int kt = 0; kt < 4; ++kt) {
        bf16x8 a[4];
#pragma unroll
        for (int mi = 0; mi < 4; ++mi)
          a[mi] = *(const bf16x8*)&znbL[(mi * 16 + arow) * 136 + kt * 32 + kseg];
#pragma unroll
        for (int ni = 0; ni < 2; ++ni) {
          bf16x8 b = *(const bf16x8*)&W1ZF[(size_t)((wave * 2 + ni) * 4 + kt) * 512 +
                                           arow * 32 + kseg];
          acc[0][ni] = mfma16(a[0], b, acc[0][ni]);
          acc[1][ni] = mfma16(a[1], b, acc[1][ni]);
          acc[2][ni] = mfma16(a[2], b, acc[2][ni]);
          acc[3][ni] = mfma16(a[3], b, acc[3][ni]);
        }
      }
#pragma unroll
      for (int ni = 0; ni < 2; ++ni) {
        int col = (wave * 2 + ni) * 16 + arow;
#pragma unroll
        for (int mi = 0; mi < 4; ++mi)
#pragma unroll
          for (int r = 0; r < 4; ++r) {
            int row = mi * 16 + crow + r;
            float2 mrv = mr[row];
            float pv = __bfloat162float(pxy[row * 264 + col]);
            float hpre = mrv.y * (acc[mi][ni][r] + pv - mrv.x * Uv[ni]) + Vv[ni];
            hx[row * 264 + col] = __float2bfloat16(gelu_erf(hpre));
          }
      }
    }
    __syncthreads();

    // B) GEMM2 (K=256, N=128): zs += 0.3*(hx@W2 + b2)
    {
      f32x4 acc2[4];
#pragma unroll
      for (int mi = 0; mi < 4; ++mi) acc2[mi] = (f32x4){0.f, 0.f, 0.f, 0.f};
#pragma unroll
      for (int kt = 0; kt < 8; ++kt) {
        bf16x8 b = *(const bf16x8*)&W2F[(size_t)(wave * 8 + kt) * 512 + arow * 32 + kseg];
#pragma unroll
        for (int mi = 0; mi < 4; ++mi) {
          bf16x8 a = *(const bf16x8*)&hx[(mi * 16 + arow) * 264 + kt * 32 + kseg];
          acc2[mi] = mfma16(a, b, acc2[mi]);
        }
      }
      int col = wave * 16 + arow;
#pragma unroll
      for (int mi = 0; mi < 4; ++mi)
#pragma unroll
        for (int r = 0; r < 4; ++r)
          zs[mi * 16 + crow + r][col] += 0.3f * (acc2[mi][r] + b2v);
    }
    __syncthreads();

    // C) LN128 + znbL + next-iter LN384 stats
    {
      float4 v[4];
#pragma unroll
      for (int q = 0; q < 4; ++q) v[q] = *(const float4*)&zs[row8][sub8 * 16 + q * 4];
      float s = 0.f, ss = 0.f;
#pragma unroll
      for (int q = 0; q < 4; ++q) {
        s += v[q].x + v[q].y + v[q].z + v[q].w;
        ss += v[q].x * v[q].x + v[q].y * v[q].y + v[q].z * v[q].z + v[q].w * v[q].w;
      }
#pragma unroll
      for (int o = 1; o < 8; o <<= 1) { s += __shfl_xor(s, o); ss += __shfl_xor(ss, o); }
      float m = s * (1.f / 128.f);
      float rstd = rsqrtf(ss * (1.f / 128.f) - m * m + LNEPS);
      float os = 0.f, oss = 0.f;
#pragma unroll
      for (int q = 0; q < 4; ++q) {
        float4 w = *(const float4*)&lzw[sub8 * 16 + q * 4];
        float4 b = *(const float4*)&lzb[sub8 * 16 + q * 4];
        float4 o4;
        o4.x = (v[q].x - m) * rstd * w.x + b.x;
        o4.y = (v[q].y - m) * rstd * w.y + b.y;
        o4.z = (v[q].z - m) * rstd * w.z + b.z;
        o4.w = (v[q].w - m) * rstd * w.w + b.w;
        *(float4*)&zs[row8][sub8 * 16 + q * 4] = o4;
        *(unsigned*)&znbL[row8 * 136 + sub8 * 16 + q * 4]     = pk_bf2(o4.x, o4.y);
        *(unsigned*)&znbL[row8 * 136 + sub8 * 16 + q * 4 + 2] = pk_bf2(o4.z, o4.w);
        os += o4.x + o4.y + o4.z + o4.w;
        oss += o4.x * o4.x + o4.y * o4.y + o4.z * o4.z + o4.w * o4.w;
      }
#pragma unroll
      for (int o = 1; o < 8; o <<= 1) { os += __shfl_xor(os, o); oss += __shfl_xor(oss, o); }
      if (sub8 == 0) {
        float2 sv = sxy[row8];
        float mm = (sv.x + os) * (1.f / 384.f);
        float var = (sv.y + oss) * (1.f / 384.f) - mm * mm;
        mr[row8] = make_float2(mm, rsqrtf(var + LNEPS));
      }
    }
    __syncthreads();
  }

  // ===== T1: affect + gate + zn update (zs in LDS), znbT bf16 =====
  {
    float zf[16];
#pragma unroll
    for (int q = 0; q < 4; ++q) {
      float4 v = *(const float4*)&zs[row8][sub8 * 16 + q * 4];
      zf[q * 4 + 0] = v.x; zf[q * 4 + 1] = v.y;
      zf[q * 4 + 2] = v.z; zf[q * 4 + 3] = v.w;
    }
    float a0 = av_g[gr * 3 + 0], a1 = av_g[gr * 3 + 1], a2 = av_g[gr * 3 + 2];
    float alf[16];
    float s = 0.f;
#pragma unroll
    for (int e = 0; e < 16; ++e) {
      int c = sub8 * 16 + e;
      alf[e] = tanhf(fmaf(a0, Wap[c], fmaf(a1, Wap[128 + c], fmaf(a2, Wap[256 + c], bap[c]))));
      s += zf[e] * Wag[c] + alf[e] * Wag[128 + c];
    }
#pragma unroll
    for (int o = 1; o < 8; o <<= 1) s += __shfl_xor(s, o);
    float g = sigmoidf_(s + bag[0]);
    float gv = (sub8 == 0) ? g : 0.f;
#pragma unroll
    for (int o = 1; o < 64; o <<= 1) gv += __shfl_xor(gv, o);
    if (lane == 0) gsum[wave] = gv;
#pragma unroll
    for (int e = 0; e < 16; ++e) zf[e] = fmaf(0.3f * g, alf[e], zf[e]);
#pragma unroll
    for (int q = 0; q < 4; ++q) {
      float4 o4;
      o4.x = zf[q * 4 + 0]; o4.y = zf[q * 4 + 1];
      o4.z = zf[q * 4 + 2]; o4.w = zf[q * 4 + 3];
      *(float4*)&zs[row8][sub8 * 16 + q * 4] = o4;
      *(unsigned*)&znbT[row8 * 136 + sub8 * 16 + q * 4]     = pk_bf2(o4.x, o4.y);
      *(unsigned*)&znbT[row8 * 136 + sub8 * 16 + q * 4 + 2] = pk_bf2(o4.z, o4.w);
    }
  }
  __syncthreads();  // B_t1
  if (t == 0) {
    float gs = 0.f;
#pragma unroll
    for (int w = 0; w < 8; ++w) gs += gsum[w];
    atomicAdd(gate_sum + k, gs);
  }

  // ===== T2: QKV MFMA (M=64, N=128; wave n-tile = wave) =====
  {
    f32x4 aq[4], ak[4], av2[4];
#pragma unroll
    for (int mi = 0; mi < 4; ++mi) {
      aq[mi] = (f32x4){0.f, 0.f, 0.f, 0.f};
      ak[mi] = (f32x4){0.f, 0.f, 0.f, 0.f};
      av2[mi] = (f32x4){0.f, 0.f, 0.f, 0.f};
    }
#pragma unroll
    for (int kt = 0; kt < 4; ++kt) {
      size_t wr = (size_t)(wave * 4 + kt) * 512 + arow * 32 + kseg;
      bf16x8 bqv = *(const bf16x8*)&WqF[wr];
      bf16x8 bkv = *(const bf16x8*)&WkF[wr];
      bf16x8 bvv = *(const bf16x8*)&WvF[wr];
#pragma unroll
      for (int mi = 0; mi < 4; ++mi) {
        bf16x8 a = *(const bf16x8*)&znbT[(mi * 16 + arow) * 136 + kt * 32 + kseg];
        aq[mi] = mfma16(a, bqv, aq[mi]);
        ak[mi] = mfma16(a, bkv, ak[mi]);
        av2[mi] = mfma16(a, bvv, av2[mi]);
      }
    }
    int col = wave * 16 + arow;
    float bqs = bq[col], bks = bk[col], bvs = bv[col];
#pragma unroll
    for (int mi = 0; mi < 4; ++mi)
#pragma unroll
      for (int r = 0; r < 4; ++r) {
        int row = mi * 16 + crow + r;
        qvb[row * 136 + col] = __float2bfloat16(aq[mi][r] + bqs);
        kcb[row * 136 + col] = __float2bfloat16(ak[mi][r] + bks);
        vcb[row * 136 + col] = __float2bfloat16(av2[mi][r] + bvs);
      }
  }
  __syncthreads();  // B_t2

  // ===== T3: history writeback + attention + LN128 + z write (k<4) =====
  if (k < 4) {
    uint4v k0 = *(const uint4v*)&kcb[row8 * 136 + sub8 * 16];
    uint4v k1 = *(const uint4v*)&kcb[row8 * 136 + sub8 * 16 + 8];
    uint4v v0 = *(const uint4v*)&vcb[row8 * 136 + sub8 * 16];
    uint4v v1 = *(const uint4v*)&vcb[row8 * 136 + sub8 * 16 + 8];
    size_t off = ((size_t)k * NB + gr) * ND + sub8 * 16;
    __builtin_nontemporal_store(k0, (uint4v*)&kh[off]);
    __builtin_nontemporal_store(k1, (uint4v*)&kh[off + 8]);
    __builtin_nontemporal_store(v0, (uint4v*)&vh[off]);
    __builtin_nontemporal_store(v1, (uint4v*)&vh[off + 8]);
  }
  {
    float zf[16];
#pragma unroll
    for (int q = 0; q < 4; ++q) {
      float4 v = *(const float4*)&zs[row8][sub8 * 16 + q * 4];
      zf[q * 4 + 0] = v.x; zf[q * 4 + 1] = v.y;
      zf[q * 4 + 2] = v.z; zf[q * 4 + 3] = v.w;
    }
    if (k > 0) {
      bf16x8 qv0 = *(const bf16x8*)&qvb[row8 * 136 + sub8 * 16];
      bf16x8 qv1 = *(const bf16x8*)&qvb[row8 * 136 + sub8 * 16 + 8];
      float p[5];
#pragma unroll
      for (int s = 0; s < 5; ++s) {
        if (s > k) break;
        bf16x8 k0, k1;
        if (s == k) {
          k0 = *(const bf16x8*)&kcb[row8 * 136 + sub8 * 16];
          k1 = *(const bf16x8*)&kcb[row8 * 136 + sub8 * 16 + 8];
        } else {
          size_t off = ((size_t)s * NB + gr) * ND + sub8 * 16;
          k0 = __builtin_bit_cast(bf16x8, __builtin_nontemporal_load((const uint4v*)&kh[off]));
          k1 = __builtin_bit_cast(bf16x8, __builtin_nontemporal_load((const uint4v*)&kh[off + 8]));
        }
        float d = 0.f;
#pragma unroll
        for (int e = 0; e < 8; ++e)
          d += bfs2f(qv0[e]) * bfs2f(k0[e]) + bfs2f(qv1[e]) * bfs2f(k1[e]);
#pragma unroll
        for (int o = 1; o < 8; o <<= 1) d += __shfl_xor(d, o);
        p[s] = d * 0.088388347648318447f;
      }
      float mx = p[0];
#pragma unroll
      for (int s = 1; s < 5; ++s) if (s <= k) mx = fmaxf(mx, p[s]);
      float sum = 0.f;
#pragma unroll
      for (int s = 0; s < 5; ++s) if (s <= k) { p[s] = expf(p[s] - mx); sum += p[s]; }
      float inv = 1.f / sum;
#pragma unroll
      for (int s = 0; s < 5; ++s) {
        if (s > k) break;
        bf16x8 v0, v1;
        if (s == k) {
          v0 = *(const bf16x8*)&vcb[row8 * 136 + sub8 * 16];
          v1 = *(const bf16x8*)&vcb[row8 * 136 + sub8 * 16 + 8];
        } else {
          size_t off = ((size_t)s * NB + gr) * ND + sub8 * 16;
          v0 = __builtin_bit_cast(bf16x8, __builtin_nontemporal_load((const uint4v*)&vh[off]));
          v1 = __builtin_bit_cast(bf16x8, __builtin_nontemporal_load((const uint4v*)&vh[off + 8]));
        }
        float w = p[s] * inv;
#pragma unroll
        for (int e = 0; e < 8; ++e) {
          zf[e]     = fmaf(w, bfs2f(v0[e]), zf[e]);
          zf[8 + e] = fmaf(w, bfs2f(v1[e]), zf[8 + e]);
        }
      }
      float s2 = 0.f, ss = 0.f;
#pragma unroll
      for (int e = 0; e < 16; ++e) { s2 += zf[e]; ss += zf[e] * zf[e]; }
#pragma unroll
      for (int o = 1; o < 8; o <<= 1) { s2 += __shfl_xor(s2, o); ss += __shfl_xor(ss, o); }
      float m = s2 * (1.f / 128.f);
      float rstd = rsqrtf(ss * (1.f / 128.f) - m * m + LNEPS);
#pragma unroll
      for (int e = 0; e < 16; ++e) {
        int c = sub8 * 16 + e;
        zf[e] = (zf[e] - m) * rstd * lzw[c] + lzb[c];
      }
#pragma unroll
      for (int q = 0; q < 4; ++q) {
        float4 o4;
        o4.x = zf[q * 4 + 0]; o4.y = zf[q * 4 + 1];
        o4.z = zf[q * 4 + 2]; o4.w = zf[q * 4 + 3];
        *(float4*)&zs[row8][sub8 * 16 + q * 4] = o4;
      }
    }
    if (k < 4) {
      // bf16 inter-step z store
      uint4v o0, o1;
      o0[0] = pk_bf2(zf[0], zf[1]);   o0[1] = pk_bf2(zf[2], zf[3]);
      o0[2] = pk_bf2(zf[4], zf[5]);   o0[3] = pk_bf2(zf[6], zf[7]);
      o1[0] = pk_bf2(zf[8], zf[9]);   o1[1] = pk_bf2(zf[10], zf[11]);
      o1[2] = pk_bf2(zf[12], zf[13]); o1[3] = pk_bf2(zf[14], zf[15]);
      *(uint4v*)&zb[gr * ND + sub8 * 16]     = o0;
      *(uint4v*)&zb[gr * ND + sub8 * 16 + 8] = o1;
    }
  }
  __syncthreads();  // B_t3

  // ===== T4: answer LN256 -> ai (two-pass over LDS) =====
  {
    float s = 0.f, ss = 0.f;
#pragma unroll
    for (int q = 0; q < 4; ++q) {
      float4 v = *(const float4*)&ys[row8][sub8 * 16 + q * 4];
      s += v.x + v.y + v.z + v.w;
      ss += v.x * v.x + v.y * v.y + v.z * v.z + v.w * v.w;
      float4 w = *(const float4*)&zs[row8][sub8 * 16 + q * 4];
      s += w.x + w.y + w.z + w.w;
      ss += w.x * w.x + w.y * w.y + w.z * w.z + w.w * w.w;
    }
#pragma unroll
    for (int o = 1; o < 8; o <<= 1) { s += __shfl_xor(s, o); ss += __shfl_xor(ss, o); }
    float m = s * (1.f / 256.f);
    float rstd = rsqrtf(ss * (1.f / 256.f) - m * m + LNEPS);
#pragma unroll
    for (int h = 0; h < 2; ++h) {
#pragma unroll
      for (int q = 0; q < 4; ++q) {
        float4 v = (h == 0)
            ? *(const float4*)&ys[row8][sub8 * 16 + q * 4]
            : *(const float4*)&zs[row8][sub8 * 16 + q * 4];
        int c0 = h * 128 + sub8 * 16 + q * 4;
        float a0 = (v.x - m) * rstd * lnw_ans[c0 + 0] + lnb_ans[c0 + 0];
        float a1 = (v.y - m) * rstd * lnw_ans[c0 + 1] + lnb_ans[c0 + 1];
        float a2 = (v.z - m) * rstd * lnw_ans[c0 + 2] + lnb_ans[c0 + 2];
        float a3 = (v.w - m) * rstd * lnw_ans[c0 + 3] + lnb_ans[c0 + 3];
        *(unsigned*)&ai[row8 * 264 + c0]     = pk_bf2(a0, a1);
        *(unsigned*)&ai[row8 * 264 + c0 + 2] = pk_bf2(a2, a3);
      }
    }
  }
  __syncthreads();  // B_t4

  // ===== T5: ans GEMM1 (M=64, K=256, N=256) -> ha =====
  {
    f32x4 acc[4][2];
#pragma unroll
    for (int mi = 0; mi < 4; ++mi)
#pragma unroll
      for (int ni = 0; ni < 2; ++ni) acc[mi][ni] = (f32x4){0.f, 0.f, 0.f, 0.f};
#pragma unroll
    for (int kt = 0; kt < 8; ++kt) {
      bf16x8 a[4];
#pragma unroll
      for (int mi = 0; mi < 4; ++mi)
        a[mi] = *(const bf16x8*)&ai[(mi * 16 + arow) * 264 + kt * 32 + kseg];
#pragma unroll
      for (int ni = 0; ni < 2; ++ni) {
        bf16x8 b = *(const bf16x8*)&WA1F[(size_t)((wave * 2 + ni) * 8 + kt) * 512 +
                                         arow * 32 + kseg];
        acc[0][ni] = mfma16(a[0], b, acc[0][ni]);
        acc[1][ni] = mfma16(a[1], b, acc[1][ni]);
        acc[2][ni] = mfma16(a[2], b, acc[2][ni]);
        acc[3][ni] = mfma16(a[3], b, acc[3][ni]);
      }
    }
#pragma unroll
    for (int ni = 0; ni < 2; ++ni) {
      int col = (wave * 2 + ni) * 16 + arow;
      float bb = ba1[col];
#pragma unroll
      for (int mi = 0; mi < 4; ++mi)
#pragma unroll
        for (int r = 0; r < 4; ++r)
          ha[(mi * 16 + crow + r) * 264 + col] =
              __float2bfloat16(gelu_erf(acc[mi][ni][r] + bb));
    }
  }
  __syncthreads();  // B_t5

  // ===== T6: ans GEMM2 (K=256, N=128): ys += 0.4*(ha@WA2 + ba2) =====
  {
    f32x4 acc[4];
#pragma unroll
    for (int mi = 0; mi < 4; ++mi) acc[mi] = (f32x4){0.f, 0.f, 0.f, 0.f};
#pragma unroll
    for (int kt = 0; kt < 8; ++kt) {
      bf16x8 b = *(const bf16x8*)&WA2F[(size_t)(wave * 8 + kt) * 512 + arow * 32 + kseg];
#pragma unroll
      for (int mi = 0; mi < 4; ++mi) {
        bf16x8 a = *(const bf16x8*)&ha[(mi * 16 + arow) * 264 + kt * 32 + kseg];
        acc[mi] = mfma16(a, b, acc[mi]);
      }
    }
    int col = wave * 16 + arow;
    float bb = ba2[col];
#pragma unroll
    for (int mi = 0; mi < 4; ++mi)
#pragma unroll
      for (int r = 0; r < 4; ++r)
        ys[mi * 16 + crow + r][col] += 0.4f * (acc[mi][r] + bb);
  }
  __syncthreads();  // B_t6

  // ===== T7: y writeback =====
#pragma unroll
  for (int q = 0; q < 4; ++q)
    *(float4*)&y[gr * ND + sub8 * 16 + q * 4] =
        *(const float4*)&ys[row8][sub8 * 16 + q * 4];

  // ===== PAD head fused at k==4 (zs holds final z in LDS) =====
  if (k == 4) {
    __syncthreads();
    {
      const int cc = t & 63, rg8 = t >> 6;
      float acc[8];
#pragma unroll
      for (int r = 0; r < 8; ++r) acc[r] = 0.f;
      for (int j0 = 0; j0 < ND; j0 += 4) {
        float w0 = Wp1[(j0 + 0) * 64 + cc], w1 = Wp1[(j0 + 1) * 64 + cc];
        float w2 = Wp1[(j0 + 2) * 64 + cc], w3 = Wp1[(j0 + 3) * 64 + cc];
#pragma unroll
        for (int r = 0; r < 8; ++r) {
          float4 a = *reinterpret_cast<const float4*>(&zs[rg8 * 8 + r][j0]);
          acc[r] = fmaf(a.x, w0, fmaf(a.y, w1, fmaf(a.z, w2, fmaf(a.w, w3, acc[r]))));
        }
      }
      float bb = bp1[cc];
#pragma unroll
      for (int r = 0; r < 8; ++r) h1[(rg8 * 8 + r) * 68 + cc] = gelu_erf(acc[r] + bb);
    }
    __syncthreads();
    {
      const int row = t >> 3, sub = t & 7;
      if (sub < 3) {
        float p = 0.f;
        for (int j = 0; j < 64; ++j) p += h1[row * 68 + j] * Wp2[j * 3 + sub];
        pad_out[(row0 + row) * 3 + sub] = tanhf(p + bp2[sub]);
      }
    }
  }
}

__global__ void finalize_confs(const float* __restrict__ gs, float* __restrict__ confs) {
  int i = threadIdx.x;
  if (i < 5) confs[i] = gs[i] * (1.0f / 32768.0f);
}

// ------------------------------------------------------------------- launch
extern "C" void kernel_launch(void* const* d_in, const int* in_sizes, int n_in,
                              void* d_out, int out_size, void* d_ws, size_t ws_size,
                              hipStream_t stream) {
  const float* x       = (const float*)d_in[0];
  const float* y_init  = (const float*)d_in[1];
  const float* av      = (const float*)d_in[2];
  const float* ln_lat_w = (const float*)d_in[3];
  const float* ln_lat_b = (const float*)d_in[4];
  const float* ln_ans_w = (const float*)d_in[5];
  const float* ln_ans_b = (const float*)d_in[6];
  const float* ln_z_w   = (const float*)d_in[7];
  const float* ln_z_b   = (const float*)d_in[8];
  const float* W_lat1 = (const float*)d_in[9];  const float* b_lat1 = (const float*)d_in[10];
  const float* W_lat2 = (const float*)d_in[11]; const float* b_lat2 = (const float*)d_in[12];
  const float* W_ans1 = (const float*)d_in[13]; const float* b_ans1 = (const float*)d_in[14];
  const float* W_ans2 = (const float*)d_in[15]; const float* b_ans2 = (const float*)d_in[16];
  const float* W_ap = (const float*)d_in[17];   const float* b_ap = (const float*)d_in[18];
  const float* W_ag = (const float*)d_in[19];   const float* b_ag = (const float*)d_in[20];
  const float* Wq = (const float*)d_in[21];     const float* bq = (const float*)d_in[22];
  const float* Wk = (const float*)d_in[23];     const float* bk = (const float*)d_in[24];
  const float* Wv = (const float*)d_in[25];     const float* bv = (const float*)d_in[26];
  const float* W_p1 = (const float*)d_in[27];   const float* b_p1 = (const float*)d_in[28];
  const float* W_p2 = (const float*)d_in[29];   const float* b_p2 = (const float*)d_in[30];

  float* y     = (float*)d_out;
  float* confs = (float*)d_out + (size_t)NB * ND;
  float* pad   = confs + 5;

  char* p = (char*)d_ws;
  float* gate_sum = (float*)p;
  bf16* zb   = (bf16*)(p + 256);                       // bf16 [B][128]
  bf16* xb   = zb + (size_t)NB * ND;                   // bf16 [B][128]
  bf16* kh   = xb + (size_t)NB * ND;
  bf16* vh   = kh + (size_t)4 * NB * ND;
  bf16* W2F  = vh + (size_t)4 * NB * ND;
  bf16* WA1F = W2F + 256 * 128;
  bf16* WA2F = WA1F + 256 * 256;
  bf16* WqF  = WA2F + 256 * 128;
  bf16* WkF  = WqF + 128 * 128;
  bf16* WvF  = WkF + 128 * 128;
  bf16* W1XYF = WvF + 128 * 128;          // 256x256
  bf16* W1ZF  = W1XYF + 256 * 256;        // 128x256
  float* U    = (float*)(W1ZF + 128 * 256);
  float* V0b  = U + 256;

  hipMemsetAsync(gate_sum, 0, 32, stream);

  prep_xb<<<NB * ND / 4 / 256, 256, 0, stream>>>(x, xb);
  prep_w1p<<<(384 * 256 + 255) / 256, 256, 0, stream>>>(W_lat1, ln_lat_w, W1XYF, W1ZF);
  prep_uv<<<1, 256, 0, stream>>>(W_lat1, ln_lat_w, ln_lat_b, b_lat1, U, V0b);
  prep_w_frag<<<(256 * 128 + 255) / 256, 256, 0, stream>>>(W_lat2, W2F, 256, 128);
  prep_w_frag<<<(256 * 256 + 255) / 256, 256, 0, stream>>>(W_ans1, WA1F, 256, 256);
  prep_w_frag<<<(256 * 128 + 255) / 256, 256, 0, stream>>>(W_ans2, WA2F, 256, 128);
  prep_w_frag<<<(128 * 128 + 255) / 256, 256, 0, stream>>>(Wq, WqF, 128, 128);
  prep_w_frag<<<(128 * 128 + 255) / 256, 256, 0, stream>>>(Wk, WkF, 128, 128);
  prep_w_frag<<<(128 * 128 + 255) / 256, 256, 0, stream>>>(Wv, WvF, 128, 128);

  for (int k = 0; k < 5; ++k) {
    const float* ysrc = (k == 0) ? y_init : y;
    trm_step<<<NB / 64, 512, 0, stream>>>(
        xb, ysrc, y, zb, W1XYF, W1ZF, U, V0b, W2F, b_lat2, ln_z_w, ln_z_b,
        av, ln_ans_w, ln_ans_b,
        WA1F, b_ans1, WA2F, b_ans2,
        W_ap, b_ap, W_ag, b_ag,
        WqF, bq, WkF, bk, WvF, bv,
        W_p1, b_p1, W_p2, b_p2, pad,
        gate_sum, kh, vh, k);
  }
  finalize_confs<<<1, 64, 0, stream>>>(gate_sum, confs);
}

// Round 21
// 760.400 us; speedup vs baseline: 1.0451x; 1.0181x over previous
//
#include <hip/hip_runtime.h>
#include <hip/hip_bf16.h>
#include <math.h>

// TinyRecursiveModelTRMv3 — Round 21: R20 (best, 774us) with the kh/vh
// nontemporal hints REMOVED. History (134 MB) fits L3; nt (evict-first)
// was forcing HBM-latency re-reads of the attention history on T3's
// critical path. Everything else identical to R20.

constexpr int NB = 32768;
constexpr int ND = 128;
constexpr float LNEPS = 1e-5f;

typedef short bf16x8 __attribute__((ext_vector_type(8)));
typedef float f32x4 __attribute__((ext_vector_type(4)));
typedef unsigned uint4v __attribute__((ext_vector_type(4)));
using bf16 = __hip_bfloat16;

static __device__ __forceinline__ float gelu_erf(float x) {
  return 0.5f * x * (1.0f + erff(x * 0.70710678118654752440f));
}
static __device__ __forceinline__ float sigmoidf_(float x) {
  return 1.0f / (1.0f + expf(-x));
}
static __device__ __forceinline__ f32x4 mfma16(bf16x8 a, bf16x8 b, f32x4 c) {
  return __builtin_amdgcn_mfma_f32_16x16x32_bf16(a, b, c, 0, 0, 0);
}
static __device__ __forceinline__ float bfs2f(short u) {
  unsigned v = ((unsigned)(unsigned short)u) << 16;
  return __builtin_bit_cast(float, v);
}
static __device__ __forceinline__ unsigned pk_bf2(float a, float b) {
  unsigned ua = __builtin_bit_cast(unsigned, a);
  unsigned ub = __builtin_bit_cast(unsigned, b);
  ua = (ua + 0x7fffu + ((ua >> 16) & 1u)) >> 16;
  ub = (ub + 0x7fffu + ((ub >> 16) & 1u)) & 0xffff0000u;
  return ub | ua;
}

// fragment-major: f = ((n>>4)*(K>>5) + (k>>5))*512 + (n&15)*32 + (k&31)
__global__ void prep_w_frag(const float* __restrict__ src, bf16* __restrict__ dst,
                            int K, int N) {
  int i = blockIdx.x * 256 + threadIdx.x;
  if (i >= K * N) return;
  int k = i / N, n = i - k * N;
  int f = ((n >> 4) * (K >> 5) + (k >> 5)) * 512 + (n & 15) * 32 + (k & 31);
  dst[f] = __float2bfloat16(src[i]);
}

// x fp32 -> bf16 (done once; trm_step reads bf16 x every step)
__global__ void prep_xb(const float* __restrict__ src, bf16* __restrict__ dst) {
  int i = blockIdx.x * 256 + threadIdx.x;   // one float4 per thread
  float4 v = *(const float4*)&src[(size_t)i * 4];
  unsigned u0 = pk_bf2(v.x, v.y), u1 = pk_bf2(v.z, v.w);
  *(unsigned*)&dst[(size_t)i * 4]     = u0;
  *(unsigned*)&dst[(size_t)i * 4 + 2] = u1;
}

// W1' = diag(lnw)·W1 split into xy (K=256) and z (K=128), frag-major
__global__ void prep_w1p(const float* __restrict__ W1, const float* __restrict__ lnw,
                         bf16* __restrict__ WXY, bf16* __restrict__ WZ) {
  int i = blockIdx.x * 256 + threadIdx.x;
  if (i >= 384 * 256) return;
  int j = i >> 8, n = i & 255;
  float v = lnw[j] * W1[i];
  if (j < 256) {
    int f = ((n >> 4) * 8 + (j >> 5)) * 512 + (n & 15) * 32 + (j & 31);
    WXY[f] = __float2bfloat16(v);
  } else {
    int k = j - 256;
    int f = ((n >> 4) * 4 + (k >> 5)) * 512 + (n & 15) * 32 + (k & 31);
    WZ[f] = __float2bfloat16(v);
  }
}

__global__ void prep_uv(const float* __restrict__ W1, const float* __restrict__ lnw,
                        const float* __restrict__ lnb, const float* __restrict__ b1,
                        float* __restrict__ U, float* __restrict__ V0b) {
  int n = threadIdx.x;
  float u = 0.f, v = 0.f;
  for (int j = 0; j < 384; ++j) {
    float w = W1[j * 256 + n];
    u = fmaf(lnw[j], w, u);
    v = fmaf(lnb[j], w, v);
  }
  U[n] = u;
  V0b[n] = v + b1[n];
}

// ---------------------------------------------------------------- trm_step
// LDS pool (153600 B) — unchanged layout:
//   zs f32[64][132] @0 | ys f32[64][132] @33792 | scr @67584 (84992):
//     latent: pxy[64][264] @+0, znbL[64][136] @+33792, hx[64][264] @+51200
//     tail:   znbT @+0, qvb @+17408, kcb @+34816, vcb @+52224
//             ai[64][264] @+0, ha[64][264] @+33792
//     pad(k=4): h1 f32[64][68] @+0
//   sxy @152576 | mr @153088
__global__ __launch_bounds__(512) void trm_step(
    const bf16* __restrict__ xb, const float* __restrict__ ysrc,
    float* __restrict__ y,
    bf16* __restrict__ zb,
    const bf16* __restrict__ W1XYF, const bf16* __restrict__ W1ZF,
    const float* __restrict__ U, const float* __restrict__ V0b,
    const bf16* __restrict__ W2F, const float* __restrict__ b2,
    const float* __restrict__ lzw, const float* __restrict__ lzb,
    const float* __restrict__ av_g,
    const float* __restrict__ lnw_ans, const float* __restrict__ lnb_ans,
    const bf16* __restrict__ WA1F, const float* __restrict__ ba1,
    const bf16* __restrict__ WA2F, const float* __restrict__ ba2,
    const float* __restrict__ Wap, const float* __restrict__ bap,
    const float* __restrict__ Wag, const float* __restrict__ bag,
    const bf16* __restrict__ WqF, const float* __restrict__ bq,
    const bf16* __restrict__ WkF, const float* __restrict__ bk,
    const bf16* __restrict__ WvF, const float* __restrict__ bv,
    const float* __restrict__ Wp1, const float* __restrict__ bp1,
    const float* __restrict__ Wp2, const float* __restrict__ bp2,
    float* __restrict__ pad_out,
    float* __restrict__ gate_sum,
    bf16* __restrict__ kh, bf16* __restrict__ vh, int k)
{
  __shared__ __align__(16) char pool[153600];
  __shared__ float gsum[8];
  float (* const zs)[132] = (float(*)[132])pool;
  float (* const ys)[132] = (float(*)[132])(pool + 33792);
  char* const scr = pool + 67584;
  bf16* const pxy  = (bf16*)scr;
  bf16* const znbL = (bf16*)(scr + 33792);
  bf16* const hx   = (bf16*)(scr + 51200);
  bf16* const znbT = (bf16*)scr;
  bf16* const qvb  = (bf16*)(scr + 17408);
  bf16* const kcb  = (bf16*)(scr + 34816);
  bf16* const vcb  = (bf16*)(scr + 52224);
  bf16* const ai   = (bf16*)scr;
  bf16* const ha   = (bf16*)(scr + 33792);
  float* const h1  = (float*)scr;                 // pad scratch [64][68]
  float2* const sxy = (float2*)(pool + 152576);
  float2* const mr  = (float2*)(pool + 153088);

  const int t = threadIdx.x;
  const int wave = t >> 6, lane = t & 63;
  const int row8 = t >> 3, sub8 = t & 7;
  const int arow = lane & 15, kseg = (lane >> 4) * 8, crow = (lane >> 4) * 4;
  const size_t row0 = (size_t)blockIdx.x * 64;
  const size_t gr = row0 + row8;

  // ===== P0: stage x(bf16), y, z(bf16); row sums; iter-0 LN384 stats =====
  {
    float s = 0.f, ss = 0.f;
    // ---- x (bf16 pre-converted; pure copy into hx + stats)
    {
      uint4v xu0 = *(const uint4v*)&xb[gr * ND + sub8 * 16];
      uint4v xu1 = *(const uint4v*)&xb[gr * ND + sub8 * 16 + 8];
      *(uint4v*)&hx[row8 * 264 + sub8 * 16]     = xu0;
      *(uint4v*)&hx[row8 * 264 + sub8 * 16 + 8] = xu1;
      bf16x8 xv0 = __builtin_bit_cast(bf16x8, xu0);
      bf16x8 xv1 = __builtin_bit_cast(bf16x8, xu1);
#pragma unroll
      for (int e = 0; e < 8; ++e) {
        float f0 = bfs2f(xv0[e]), f1 = bfs2f(xv1[e]);
        s += f0 + f1;
        ss += f0 * f0 + f1 * f1;
      }
    }
    // ---- y (fp32; from y_init at k==0, else y)
#pragma unroll
    for (int q = 0; q < 4; ++q) {
      float4 v = *(const float4*)&ysrc[gr * ND + sub8 * 16 + q * 4];
      s += v.x + v.y + v.z + v.w;
      ss += v.x * v.x + v.y * v.y + v.z * v.z + v.w * v.w;
      *(unsigned*)&hx[row8 * 264 + 128 + sub8 * 16 + q * 4]     = pk_bf2(v.x, v.y);
      *(unsigned*)&hx[row8 * 264 + 128 + sub8 * 16 + q * 4 + 2] = pk_bf2(v.z, v.w);
      *(float4*)&ys[row8][sub8 * 16 + q * 4] = v;
    }
#pragma unroll
    for (int o = 1; o < 8; o <<= 1) { s += __shfl_xor(s, o); ss += __shfl_xor(ss, o); }
    // ---- z (bf16 inter-step storage)
    float zsum = 0.f, zss = 0.f;
    {
      uint4v zu0, zu1;
      if (k > 0) {
        zu0 = *(const uint4v*)&zb[gr * ND + sub8 * 16];
        zu1 = *(const uint4v*)&zb[gr * ND + sub8 * 16 + 8];
      } else {
        zu0 = (uint4v){0u, 0u, 0u, 0u};
        zu1 = (uint4v){0u, 0u, 0u, 0u};
      }
      *(uint4v*)&znbL[row8 * 136 + sub8 * 16]     = zu0;
      *(uint4v*)&znbL[row8 * 136 + sub8 * 16 + 8] = zu1;
      bf16x8 zv0 = __builtin_bit_cast(bf16x8, zu0);
      bf16x8 zv1 = __builtin_bit_cast(bf16x8, zu1);
#pragma unroll
      for (int q = 0; q < 2; ++q) {
        float4 v;
        v.x = bfs2f(zv0[q * 4 + 0]); v.y = bfs2f(zv0[q * 4 + 1]);
        v.z = bfs2f(zv0[q * 4 + 2]); v.w = bfs2f(zv0[q * 4 + 3]);
        *(float4*)&zs[row8][sub8 * 16 + q * 4] = v;
        zsum += v.x + v.y + v.z + v.w;
        zss += v.x * v.x + v.y * v.y + v.z * v.z + v.w * v.w;
        float4 w;
        w.x = bfs2f(zv1[q * 4 + 0]); w.y = bfs2f(zv1[q * 4 + 1]);
        w.z = bfs2f(zv1[q * 4 + 2]); w.w = bfs2f(zv1[q * 4 + 3]);
        *(float4*)&zs[row8][sub8 * 16 + 8 + q * 4] = w;
        zsum += w.x + w.y + w.z + w.w;
        zss += w.x * w.x + w.y * w.y + w.z * w.z + w.w * w.w;
      }
    }
#pragma unroll
    for (int o = 1; o < 8; o <<= 1) { zsum += __shfl_xor(zsum, o); zss += __shfl_xor(zss, o); }
    if (sub8 == 0) {
      sxy[row8] = make_float2(s, ss);
      float mm = (s + zsum) * (1.f / 384.f);
      float var = (ss + zss) * (1.f / 384.f) - mm * mm;
      mr[row8] = make_float2(mm, rsqrtf(var + LNEPS));
    }
  }
  __syncthreads();

  // ===== P1: pregemm pxy = [x,y] @ W1'xy (K=256, N=256) =====
  {
    f32x4 acc[4][2];
#pragma unroll
    for (int mi = 0; mi < 4; ++mi)
#pragma unroll
      for (int ni = 0; ni < 2; ++ni) acc[mi][ni] = (f32x4){0.f, 0.f, 0.f, 0.f};
#pragma unroll
    for (int kt = 0; kt < 8; ++kt) {
      bf16x8 a[4];
#pragma unroll
      for (int mi = 0; mi < 4; ++mi)
        a[mi] = *(const bf16x8*)&hx[(mi * 16 + arow) * 264 + kt * 32 + kseg];
#pragma unroll
      for (int ni = 0; ni < 2; ++ni) {
        bf16x8 b = *(const bf16x8*)&W1XYF[(size_t)((wave * 2 + ni) * 8 + kt) * 512 +
                                          arow * 32 + kseg];
        acc[0][ni] = mfma16(a[0], b, acc[0][ni]);
        acc[1][ni] = mfma16(a[1], b, acc[1][ni]);
        acc[2][ni] = mfma16(a[2], b, acc[2][ni]);
        acc[3][ni] = mfma16(a[3], b, acc[3][ni]);
      }
    }
#pragma unroll
    for (int ni = 0; ni < 2; ++ni) {
      int col = (wave * 2 + ni) * 16 + arow;
#pragma unroll
      for (int mi = 0; mi < 4; ++mi)
#pragma unroll
        for (int r = 0; r < 4; ++r)
          pxy[(mi * 16 + crow + r) * 264 + col] = __float2bfloat16(acc[mi][ni][r]);
    }
  }
  __syncthreads();

  float Uv[2], Vv[2];
#pragma unroll
  for (int ni = 0; ni < 2; ++ni) {
    int col = (wave * 2 + ni) * 16 + arow;
    Uv[ni] = U[col];
    Vv[ni] = V0b[col];
  }
  const float b2v = b2[wave * 16 + arow];

  // ===== 4 latent iterations =====
  for (int n = 0; n < 4; ++n) {
    // A) pz GEMM (K=128) + folded-LN epilogue -> hx = gelu(...)
    {
      f32x4 acc[4][2];
#pragma unroll
      for (int mi = 0; mi < 4; ++mi)
#pragma unroll
        for (int ni = 0; ni < 2; ++ni) acc[mi][ni] = (f32x4){0.f, 0.f, 0.f, 0.f};
#pragma unroll
      for (int kt = 0; kt < 4; ++kt) {
        bf16x8 a[4];
#pragma unroll
        for (int mi = 0; mi < 4; ++mi)
          a[mi] = *(const bf16x8*)&znbL[(mi * 16 + arow) * 136 + kt * 32 + kseg];
#pragma unroll
        for (int ni = 0; ni < 2; ++ni) {
          bf16x8 b = *(const bf16x8*)&W1ZF[(size_t)((wave * 2 + ni) * 4 + kt) * 512 +
                                           arow * 32 + kseg];
          acc[0][ni] = mfma16(a[0], b, acc[0][ni]);
          acc[1][ni] = mfma16(a[1], b, acc[1][ni]);
          acc[2][ni] = mfma16(a[2], b, acc[2][ni]);
          acc[3][ni] = mfma16(a[3], b, acc[3][ni]);
        }
      }
#pragma unroll
      for (int ni = 0; ni < 2; ++ni) {
        int col = (wave * 2 + ni) * 16 + arow;
#pragma unroll
        for (int mi = 0; mi < 4; ++mi)
#pragma unroll
          for (int r = 0; r < 4; ++r) {
            int row = mi * 16 + crow + r;
            float2 mrv = mr[row];
            float pv = __bfloat162float(pxy[row * 264 + col]);
            float hpre = mrv.y * (acc[mi][ni][r] + pv - mrv.x * Uv[ni]) + Vv[ni];
            hx[row * 264 + col] = __float2bfloat16(gelu_erf(hpre));
          }
      }
    }
    __syncthreads();

    // B) GEMM2 (K=256, N=128): zs += 0.3*(hx@W2 + b2)
    {
      f32x4 acc2[4];
#pragma unroll
      for (int mi = 0; mi < 4; ++mi) acc2[mi] = (f32x4){0.f, 0.f, 0.f, 0.f};
#pragma unroll
      for (int kt = 0; kt < 8; ++kt) {
        bf16x8 b = *(const bf16x8*)&W2F[(size_t)(wave * 8 + kt) * 512 + arow * 32 + kseg];
#pragma unroll
        for (int mi = 0; mi < 4; ++mi) {
          bf16x8 a = *(const bf16x8*)&hx[(mi * 16 + arow) * 264 + kt * 32 + kseg];
          acc2[mi] = mfma16(a, b, acc2[mi]);
        }
      }
      int col = wave * 16 + arow;
#pragma unroll
      for (int mi = 0; mi < 4; ++mi)
#pragma unroll
        for (int r = 0; r < 4; ++r)
          zs[mi * 16 + crow + r][col] += 0.3f * (acc2[mi][r] + b2v);
    }
    __syncthreads();

    // C) LN128 + znbL + next-iter LN384 stats
    {
      float4 v[4];
#pragma unroll
      for (int q = 0; q < 4; ++q) v[q] = *(const float4*)&zs[row8][sub8 * 16 + q * 4];
      float s = 0.f, ss = 0.f;
#pragma unroll
      for (int q = 0; q < 4; ++q) {
        s += v[q].x + v[q].y + v[q].z + v[q].w;
        ss += v[q].x * v[q].x + v[q].y * v[q].y + v[q].z * v[q].z + v[q].w * v[q].w;
      }
#pragma unroll
      for (int o = 1; o < 8; o <<= 1) { s += __shfl_xor(s, o); ss += __shfl_xor(ss, o); }
      float m = s * (1.f / 128.f);
      float rstd = rsqrtf(ss * (1.f / 128.f) - m * m + LNEPS);
      float os = 0.f, oss = 0.f;
#pragma unroll
      for (int q = 0; q < 4; ++q) {
        float4 w = *(const float4*)&lzw[sub8 * 16 + q * 4];
        float4 b = *(const float4*)&lzb[sub8 * 16 + q * 4];
        float4 o4;
        o4.x = (v[q].x - m) * rstd * w.x + b.x;
        o4.y = (v[q].y - m) * rstd * w.y + b.y;
        o4.z = (v[q].z - m) * rstd * w.z + b.z;
        o4.w = (v[q].w - m) * rstd * w.w + b.w;
        *(float4*)&zs[row8][sub8 * 16 + q * 4] = o4;
        *(unsigned*)&znbL[row8 * 136 + sub8 * 16 + q * 4]     = pk_bf2(o4.x, o4.y);
        *(unsigned*)&znbL[row8 * 136 + sub8 * 16 + q * 4 + 2] = pk_bf2(o4.z, o4.w);
        os += o4.x + o4.y + o4.z + o4.w;
        oss += o4.x * o4.x + o4.y * o4.y + o4.z * o4.z + o4.w * o4.w;
      }
#pragma unroll
      for (int o = 1; o < 8; o <<= 1) { os += __shfl_xor(os, o); oss += __shfl_xor(oss, o); }
      if (sub8 == 0) {
        float2 sv = sxy[row8];
        float mm = (sv.x + os) * (1.f / 384.f);
        float var = (sv.y + oss) * (1.f / 384.f) - mm * mm;
        mr[row8] = make_float2(mm, rsqrtf(var + LNEPS));
      }
    }
    __syncthreads();
  }

  // ===== T1: affect + gate + zn update (zs in LDS), znbT bf16 =====
  {
    float zf[16];
#pragma unroll
    for (int q = 0; q < 4; ++q) {
      float4 v = *(const float4*)&zs[row8][sub8 * 16 + q * 4];
      zf[q * 4 + 0] = v.x; zf[q * 4 + 1] = v.y;
      zf[q * 4 + 2] = v.z; zf[q * 4 + 3] = v.w;
    }
    float a0 = av_g[gr * 3 + 0], a1 = av_g[gr * 3 + 1], a2 = av_g[gr * 3 + 2];
    float alf[16];
    float s = 0.f;
#pragma unroll
    for (int e = 0; e < 16; ++e) {
      int c = sub8 * 16 + e;
      alf[e] = tanhf(fmaf(a0, Wap[c], fmaf(a1, Wap[128 + c], fmaf(a2, Wap[256 + c], bap[c]))));
      s += zf[e] * Wag[c] + alf[e] * Wag[128 + c];
    }
#pragma unroll
    for (int o = 1; o < 8; o <<= 1) s += __shfl_xor(s, o);
    float g = sigmoidf_(s + bag[0]);
    float gv = (sub8 == 0) ? g : 0.f;
#pragma unroll
    for (int o = 1; o < 64; o <<= 1) gv += __shfl_xor(gv, o);
    if (lane == 0) gsum[wave] = gv;
#pragma unroll
    for (int e = 0; e < 16; ++e) zf[e] = fmaf(0.3f * g, alf[e], zf[e]);
#pragma unroll
    for (int q = 0; q < 4; ++q) {
      float4 o4;
      o4.x = zf[q * 4 + 0]; o4.y = zf[q * 4 + 1];
      o4.z = zf[q * 4 + 2]; o4.w = zf[q * 4 + 3];
      *(float4*)&zs[row8][sub8 * 16 + q * 4] = o4;
      *(unsigned*)&znbT[row8 * 136 + sub8 * 16 + q * 4]     = pk_bf2(o4.x, o4.y);
      *(unsigned*)&znbT[row8 * 136 + sub8 * 16 + q * 4 + 2] = pk_bf2(o4.z, o4.w);
    }
  }
  __syncthreads();  // B_t1
  if (t == 0) {
    float gs = 0.f;
#pragma unroll
    for (int w = 0; w < 8; ++w) gs += gsum[w];
    atomicAdd(gate_sum + k, gs);
  }

  // ===== T2: QKV MFMA (M=64, N=128; wave n-tile = wave) =====
  {
    f32x4 aq[4], ak[4], av2[4];
#pragma unroll
    for (int mi = 0; mi < 4; ++mi) {
      aq[mi] = (f32x4){0.f, 0.f, 0.f, 0.f};
      ak[mi] = (f32x4){0.f, 0.f, 0.f, 0.f};
      av2[mi] = (f32x4){0.f, 0.f, 0.f, 0.f};
    }
#pragma unroll
    for (int kt = 0; kt < 4; ++kt) {
      size_t wr = (size_t)(wave * 4 + kt) * 512 + arow * 32 + kseg;
      bf16x8 bqv = *(const bf16x8*)&WqF[wr];
      bf16x8 bkv = *(const bf16x8*)&WkF[wr];
      bf16x8 bvv = *(const bf16x8*)&WvF[wr];
#pragma unroll
      for (int mi = 0; mi < 4; ++mi) {
        bf16x8 a = *(const bf16x8*)&znbT[(mi * 16 + arow) * 136 + kt * 32 + kseg];
        aq[mi] = mfma16(a, bqv, aq[mi]);
        ak[mi] = mfma16(a, bkv, ak[mi]);
        av2[mi] = mfma16(a, bvv, av2[mi]);
      }
    }
    int col = wave * 16 + arow;
    float bqs = bq[col], bks = bk[col], bvs = bv[col];
#pragma unroll
    for (int mi = 0; mi < 4; ++mi)
#pragma unroll
      for (int r = 0; r < 4; ++r) {
        int row = mi * 16 + crow + r;
        qvb[row * 136 + col] = __float2bfloat16(aq[mi][r] + bqs);
        kcb[row * 136 + col] = __float2bfloat16(ak[mi][r] + bks);
        vcb[row * 136 + col] = __float2bfloat16(av2[mi][r] + bvs);
      }
  }
  __syncthreads();  // B_t2

  // ===== T3: history writeback + attention + LN128 + z write (k<4) =====
  if (k < 4) {
    uint4v k0 = *(const uint4v*)&kcb[row8 * 136 + sub8 * 16];
    uint4v k1 = *(const uint4v*)&kcb[row8 * 136 + sub8 * 16 + 8];
    uint4v v0 = *(const uint4v*)&vcb[row8 * 136 + sub8 * 16];
    uint4v v1 = *(const uint4v*)&vcb[row8 * 136 + sub8 * 16 + 8];
    size_t off = ((size_t)k * NB + gr) * ND + sub8 * 16;
    *(uint4v*)&kh[off]     = k0;
    *(uint4v*)&kh[off + 8] = k1;
    *(uint4v*)&vh[off]     = v0;
    *(uint4v*)&vh[off + 8] = v1;
  }
  {
    float zf[16];
#pragma unroll
    for (int q = 0; q < 4; ++q) {
      float4 v = *(const float4*)&zs[row8][sub8 * 16 + q * 4];
      zf[q * 4 + 0] = v.x; zf[q * 4 + 1] = v.y;
      zf[q * 4 + 2] = v.z; zf[q * 4 + 3] = v.w;
    }
    if (k > 0) {
      bf16x8 qv0 = *(const bf16x8*)&qvb[row8 * 136 + sub8 * 16];
      bf16x8 qv1 = *(const bf16x8*)&qvb[row8 * 136 + sub8 * 16 + 8];
      float p[5];
#pragma unroll
      for (int s = 0; s < 5; ++s) {
        if (s > k) break;
        bf16x8 k0, k1;
        if (s == k) {
          k0 = *(const bf16x8*)&kcb[row8 * 136 + sub8 * 16];
          k1 = *(const bf16x8*)&kcb[row8 * 136 + sub8 * 16 + 8];
        } else {
          size_t off = ((size_t)s * NB + gr) * ND + sub8 * 16;
          k0 = *(const bf16x8*)&kh[off];
          k1 = *(const bf16x8*)&kh[off + 8];
        }
        float d = 0.f;
#pragma unroll
        for (int e = 0; e < 8; ++e)
          d += bfs2f(qv0[e]) * bfs2f(k0[e]) + bfs2f(qv1[e]) * bfs2f(k1[e]);
#pragma unroll
        for (int o = 1; o < 8; o <<= 1) d += __shfl_xor(d, o);
        p[s] = d * 0.088388347648318447f;
      }
      float mx = p[0];
#pragma unroll
      for (int s = 1; s < 5; ++s) if (s <= k) mx = fmaxf(mx, p[s]);
      float sum = 0.f;
#pragma unroll
      for (int s = 0; s < 5; ++s) if (s <= k) { p[s] = expf(p[s] - mx); sum += p[s]; }
      float inv = 1.f / sum;
#pragma unroll
      for (int s = 0; s < 5; ++s) {
        if (s > k) break;
        bf16x8 v0, v1;
        if (s == k) {
          v0 = *(const bf16x8*)&vcb[row8 * 136 + sub8 * 16];
          v1 = *(const bf16x8*)&vcb[row8 * 136 + sub8 * 16 + 8];
        } else {
          size_t off = ((size_t)s * NB + gr) * ND + sub8 * 16;
          v0 = *(const bf16x8*)&vh[off];
          v1 = *(const bf16x8*)&vh[off + 8];
        }
        float w = p[s] * inv;
#pragma unroll
        for (int e = 0; e < 8; ++e) {
          zf[e]     = fmaf(w, bfs2f(v0[e]), zf[e]);
          zf[8 + e] = fmaf(w, bfs2f(v1[e]), zf[8 + e]);
        }
      }
      float s2 = 0.f, ss = 0.f;
#pragma unroll
      for (int e = 0; e < 16; ++e) { s2 += zf[e]; ss += zf[e] * zf[e]; }
#pragma unroll
      for (int o = 1; o < 8; o <<= 1) { s2 += __shfl_xor(s2, o); ss += __shfl_xor(ss, o); }
      float m = s2 * (1.f / 128.f);
      float rstd = rsqrtf(ss * (1.f / 128.f) - m * m + LNEPS);
#pragma unroll
      for (int e = 0; e < 16; ++e) {
        int c = sub8 * 16 + e;
        zf[e] = (zf[e] - m) * rstd * lzw[c] + lzb[c];
      }
#pragma unroll
      for (int q = 0; q < 4; ++q) {
        float4 o4;
        o4.x = zf[q * 4 + 0]; o4.y = zf[q * 4 + 1];
        o4.z = zf[q * 4 + 2]; o4.w = zf[q * 4 + 3];
        *(float4*)&zs[row8][sub8 * 16 + q * 4] = o4;
      }
    }
    if (k < 4) {
      // bf16 inter-step z store
      uint4v o0, o1;
      o0[0] = pk_bf2(zf[0], zf[1]);   o0[1] = pk_bf2(zf[2], zf[3]);
      o0[2] = pk_bf2(zf[4], zf[5]);   o0[3] = pk_bf2(zf[6], zf[7]);
      o1[0] = pk_bf2(zf[8], zf[9]);   o1[1] = pk_bf2(zf[10], zf[11]);
      o1[2] = pk_bf2(zf[12], zf[13]); o1[3] = pk_bf2(zf[14], zf[15]);
      *(uint4v*)&zb[gr * ND + sub8 * 16]     = o0;
      *(uint4v*)&zb[gr * ND + sub8 * 16 + 8] = o1;
    }
  }
  __syncthreads();  // B_t3

  // ===== T4: answer LN256 -> ai (two-pass over LDS) =====
  {
    float s = 0.f, ss = 0.f;
#pragma unroll
    for (int q = 0; q < 4; ++q) {
      float4 v = *(const float4*)&ys[row8][sub8 * 16 + q * 4];
      s += v.x + v.y + v.z + v.w;
      ss += v.x * v.x + v.y * v.y + v.z * v.z + v.w * v.w;
      float4 w = *(const float4*)&zs[row8][sub8 * 16 + q * 4];
      s += w.x + w.y + w.z + w.w;
      ss += w.x * w.x + w.y * w.y + w.z * w.z + w.w * w.w;
    }
#pragma unroll
    for (int o = 1; o < 8; o <<= 1) { s += __shfl_xor(s, o); ss += __shfl_xor(ss, o); }
    float m = s * (1.f / 256.f);
    float rstd = rsqrtf(ss * (1.f / 256.f) - m * m + LNEPS);
#pragma unroll
    for (int h = 0; h < 2; ++h) {
#pragma unroll
      for (int q = 0; q < 4; ++q) {
        float4 v = (h == 0)
            ? *(const float4*)&ys[row8][sub8 * 16 + q * 4]
            : *(const float4*)&zs[row8][sub8 * 16 + q * 4];
        int c0 = h * 128 + sub8 * 16 + q * 4;
        float a0 = (v.x - m) * rstd * lnw_ans[c0 + 0] + lnb_ans[c0 + 0];
        float a1 = (v.y - m) * rstd * lnw_ans[c0 + 1] + lnb_ans[c0 + 1];
        float a2 = (v.z - m) * rstd * lnw_ans[c0 + 2] + lnb_ans[c0 + 2];
        float a3 = (v.w - m) * rstd * lnw_ans[c0 + 3] + lnb_ans[c0 + 3];
        *(unsigned*)&ai[row8 * 264 + c0]     = pk_bf2(a0, a1);
        *(unsigned*)&ai[row8 * 264 + c0 + 2] = pk_bf2(a2, a3);
      }
    }
  }
  __syncthreads();  // B_t4

  // ===== T5: ans GEMM1 (M=64, K=256, N=256) -> ha =====
  {
    f32x4 acc[4][2];
#pragma unroll
    for (int mi = 0; mi < 4; ++mi)
#pragma unroll
      for (int ni = 0; ni < 2; ++ni) acc[mi][ni] = (f32x4){0.f, 0.f, 0.f, 0.f};
#pragma unroll
    for (int kt = 0; kt < 8; ++kt) {
      bf16x8 a[4];
#pragma unroll
      for (int mi = 0; mi < 4; ++mi)
        a[mi] = *(const bf16x8*)&ai[(mi * 16 + arow) * 264 + kt * 32 + kseg];
#pragma unroll
      for (int ni = 0; ni < 2; ++ni) {
        bf16x8 b = *(const bf16x8*)&WA1F[(size_t)((wave * 2 + ni) * 8 + kt) * 512 +
                                         arow * 32 + kseg];
        acc[0][ni] = mfma16(a[0], b, acc[0][ni]);
        acc[1][ni] = mfma16(a[1], b, acc[1][ni]);
        acc[2][ni] = mfma16(a[2], b, acc[2][ni]);
        acc[3][ni] = mfma16(a[3], b, acc[3][ni]);
      }
    }
#pragma unroll
    for (int ni = 0; ni < 2; ++ni) {
      int col = (wave * 2 + ni) * 16 + arow;
      float bb = ba1[col];
#pragma unroll
      for (int mi = 0; mi < 4; ++mi)
#pragma unroll
        for (int r = 0; r < 4; ++r)
          ha[(mi * 16 + crow + r) * 264 + col] =
              __float2bfloat16(gelu_erf(acc[mi][ni][r] + bb));
    }
  }
  __syncthreads();  // B_t5

  // ===== T6: ans GEMM2 (K=256, N=128): ys += 0.4*(ha@WA2 + ba2) =====
  {
    f32x4 acc[4];
#pragma unroll
    for (int mi = 0; mi < 4; ++mi) acc[mi] = (f32x4){0.f, 0.f, 0.f, 0.f};
#pragma unroll
    for (int kt = 0; kt < 8; ++kt) {
      bf16x8 b = *(const bf16x8*)&WA2F[(size_t)(wave * 8 + kt) * 512 + arow * 32 + kseg];
#pragma unroll
      for (int mi = 0; mi < 4; ++mi) {
        bf16x8 a = *(const bf16x8*)&ha[(mi * 16 + arow) * 264 + kt * 32 + kseg];
        acc[mi] = mfma16(a, b, acc[mi]);
      }
    }
    int col = wave * 16 + arow;
    float bb = ba2[col];
#pragma unroll
    for (int mi = 0; mi < 4; ++mi)
#pragma unroll
      for (int r = 0; r < 4; ++r)
        ys[mi * 16 + crow + r][col] += 0.4f * (acc[mi][r] + bb);
  }
  __syncthreads();  // B_t6

  // ===== T7: y writeback =====
#pragma unroll
  for (int q = 0; q < 4; ++q)
    *(float4*)&y[gr * ND + sub8 * 16 + q * 4] =
        *(const float4*)&ys[row8][sub8 * 16 + q * 4];

  // ===== PAD head fused at k==4 (zs holds final z in LDS) =====
  if (k == 4) {
    __syncthreads();
    {
      const int cc = t & 63, rg8 = t >> 6;
      float acc[8];
#pragma unroll
      for (int r = 0; r < 8; ++r) acc[r] = 0.f;
      for (int j0 = 0; j0 < ND; j0 += 4) {
        float w0 = Wp1[(j0 + 0) * 64 + cc], w1 = Wp1[(j0 + 1) * 64 + cc];
        float w2 = Wp1[(j0 + 2) * 64 + cc], w3 = Wp1[(j0 + 3) * 64 + cc];
#pragma unroll
        for (int r = 0; r < 8; ++r) {
          float4 a = *reinterpret_cast<const float4*>(&zs[rg8 * 8 + r][j0]);
          acc[r] = fmaf(a.x, w0, fmaf(a.y, w1, fmaf(a.z, w2, fmaf(a.w, w3, acc[r]))));
        }
      }
      float bb = bp1[cc];
#pragma unroll
      for (int r = 0; r < 8; ++r) h1[(rg8 * 8 + r) * 68 + cc] = gelu_erf(acc[r] + bb);
    }
    __syncthreads();
    {
      const int row = t >> 3, sub = t & 7;
      if (sub < 3) {
        float p = 0.f;
        for (int j = 0; j < 64; ++j) p += h1[row * 68 + j] * Wp2[j * 3 + sub];
        pad_out[(row0 + row) * 3 + sub] = tanhf(p + bp2[sub]);
      }
    }
  }
}

__global__ void finalize_confs(const float* __restrict__ gs, float* __restrict__ confs) {
  int i = threadIdx.x;
  if (i < 5) confs[i] = gs[i] * (1.0f / 32768.0f);
}

// ------------------------------------------------------------------- launch
extern "C" void kernel_launch(void* const* d_in, const int* in_sizes, int n_in,
                              void* d_out, int out_size, void* d_ws, size_t ws_size,
                              hipStream_t stream) {
  const float* x       = (const float*)d_in[0];
  const float* y_init  = (const float*)d_in[1];
  const float* av      = (const float*)d_in[2];
  const float* ln_lat_w = (const float*)d_in[3];
  const float* ln_lat_b = (const float*)d_in[4];
  const float* ln_ans_w = (const float*)d_in[5];
  const float* ln_ans_b = (const float*)d_in[6];
  const float* ln_z_w   = (const float*)d_in[7];
  const float* ln_z_b   = (const float*)d_in[8];
  const float* W_lat1 = (const float*)d_in[9];  const float* b_lat1 = (const float*)d_in[10];
  const float* W_lat2 = (const float*)d_in[11]; const float* b_lat2 = (const float*)d_in[12];
  const float* W_ans1 = (const float*)d_in[13]; const float* b_ans1 = (const float*)d_in[14];
  const float* W_ans2 = (const float*)d_in[15]; const float* b_ans2 = (const float*)d_in[16];
  const float* W_ap = (const float*)d_in[17];   const float* b_ap = (const float*)d_in[18];
  const float* W_ag = (const float*)d_in[19];   const float* b_ag = (const float*)d_in[20];
  const float* Wq = (const float*)d_in[21];     const float* bq = (const float*)d_in[22];
  const float* Wk = (const float*)d_in[23];     const float* bk = (const float*)d_in[24];
  const float* Wv = (const float*)d_in[25];     const float* bv = (const float*)d_in[26];
  const float* W_p1 = (const float*)d_in[27];   const float* b_p1 = (const float*)d_in[28];
  const float* W_p2 = (const float*)d_in[29];   const float* b_p2 = (const float*)d_in[30];

  float* y     = (float*)d_out;
  float* confs = (float*)d_out + (size_t)NB * ND;
  float* pad   = confs + 5;

  char* p = (char*)d_ws;
  float* gate_sum = (float*)p;
  bf16* zb   = (bf16*)(p + 256);                       // bf16 [B][128]
  bf16* xb   = zb + (size_t)NB * ND;                   // bf16 [B][128]
  bf16* kh   = xb + (size_t)NB * ND;
  bf16* vh   = kh + (size_t)4 * NB * ND;
  bf16* W2F  = vh + (size_t)4 * NB * ND;
  bf16* WA1F = W2F + 256 * 128;
  bf16* WA2F = WA1F + 256 * 256;
  bf16* WqF  = WA2F + 256 * 128;
  bf16* WkF  = WqF + 128 * 128;
  bf16* WvF  = WkF + 128 * 128;
  bf16* W1XYF = WvF + 128 * 128;          // 256x256
  bf16* W1ZF  = W1XYF + 256 * 256;        // 128x256
  float* U    = (float*)(W1ZF + 128 * 256);
  float* V0b  = U + 256;

  hipMemsetAsync(gate_sum, 0, 32, stream);

  prep_xb<<<NB * ND / 4 / 256, 256, 0, stream>>>(x, xb);
  prep_w1p<<<(384 * 256 + 255) / 256, 256, 0, stream>>>(W_lat1, ln_lat_w, W1XYF, W1ZF);
  prep_uv<<<1, 256, 0, stream>>>(W_lat1, ln_lat_w, ln_lat_b, b_lat1, U, V0b);
  prep_w_frag<<<(256 * 128 + 255) / 256, 256, 0, stream>>>(W_lat2, W2F, 256, 128);
  prep_w_frag<<<(256 * 256 + 255) / 256, 256, 0, stream>>>(W_ans1, WA1F, 256, 256);
  prep_w_frag<<<(256 * 128 + 255) / 256, 256, 0, stream>>>(W_ans2, WA2F, 256, 128);
  prep_w_frag<<<(128 * 128 + 255) / 256, 256, 0, stream>>>(Wq, WqF, 128, 128);
  prep_w_frag<<<(128 * 128 + 255) / 256, 256, 0, stream>>>(Wk, WkF, 128, 128);
  prep_w_frag<<<(128 * 128 + 255) / 256, 256, 0, stream>>>(Wv, WvF, 128, 128);

  for (int k = 0; k < 5; ++k) {
    const float* ysrc = (k == 0) ? y_init : y;
    trm_step<<<NB / 64, 512, 0, stream>>>(
        xb, ysrc, y, zb, W1XYF, W1ZF, U, V0b, W2F, b_lat2, ln_z_w, ln_z_b,
        av, ln_ans_w, ln_ans_b,
        WA1F, b_ans1, WA2F, b_ans2,
        W_ap, b_ap, W_ag, b_ag,
        WqF, bq, WkF, bk, WvF, bv,
        W_p1, b_p1, W_p2, b_p2, pad,
        gate_sum, kh, vh, k);
  }
  finalize_confs<<<1, 64, 0, stream>>>(gate_sum, confs);
}